// Round 2
// baseline (23641.476 us; speedup 1.0000x reference)
//
#include <hip/hip_runtime.h>
#include <hip/hip_bf16.h>
#include <hip/hip_fp16.h>

// Problem constants
#define BB   128
#define TT   256
#define EE   300
#define HH   512
#define GG   2048            // 4*H gates
#define NC   11
#define MM   (BB*TT)         // 32768
#define START_TAG 9
#define STOP_TAG  10
#define NEGV (-100000.0f)

typedef _Float16 h2_t __attribute__((ext_vector_type(2)));
typedef _Float16 h4_t __attribute__((ext_vector_type(4)));
typedef _Float16 h8_t __attribute__((ext_vector_type(8)));

__device__ __forceinline__ float sigf(float x) { return 1.0f / (1.0f + __expf(-x)); }

// ---------------- zero the loss accumulator ----------------
__global__ void zero_loss_kernel(float* out) { out[MM] = 0.0f; }

// ---------------- pack W_hh (2048x512 f32) -> WT (k-major f16 pairs) ----------------
// WT h2 element (k2, g) = {W[g][2k2], W[g][2k2+1]}
__global__ __launch_bounds__(256) void pack_whh_kernel(const float* __restrict__ W,
                                                       _Float16* __restrict__ WT) {
    int idx = blockIdx.x * 256 + threadIdx.x;     // 256*2048 h2 elems
    if (idx >= 256 * GG) return;
    int k2 = idx >> 11, g = idx & (GG - 1);
    h2_t v;
    v[0] = (_Float16)W[(size_t)g * HH + 2 * k2];
    v[1] = (_Float16)W[(size_t)g * HH + 2 * k2 + 1];
    *(h2_t*)(WT + (size_t)idx * 2) = v;
}

// ---------------- layer-0 GEMM with fused embedding gather ----------------
// C[m,n] = sum_k emb[tok[m]][k] * W[n,k] + b1[n] + b2[n]   (K=300, N=2048), f16 out
__global__ __launch_bounds__(256) void gemm_l0_kernel(const int* __restrict__ tok,
                                                      const float* __restrict__ emb,
                                                      const float* __restrict__ W,
                                                      const float* __restrict__ b1,
                                                      const float* __restrict__ b2,
                                                      _Float16* __restrict__ C) {
    __shared__ float As[16][132];
    __shared__ float Bs[16][132];
    __shared__ int   toks[128];
    const int tid = threadIdx.x;
    const int m0 = blockIdx.y * 128, n0 = blockIdx.x * 128;
    if (tid < 128) toks[tid] = tok[m0 + tid];
    const int ty = tid >> 4, tx = tid & 15;
    float acc[8][8];
#pragma unroll
    for (int i = 0; i < 8; ++i)
#pragma unroll
        for (int j = 0; j < 8; ++j) acc[i][j] = 0.0f;
    __syncthreads();

    for (int k0 = 0; k0 < EE; k0 += 16) {
#pragma unroll
        for (int r = 0; r < 2; ++r) {
            int idx = tid + r * 256;
            int row = idx >> 2;
            int kc = (idx & 3) << 2;
            int kk = k0 + kc;
            float4 va = make_float4(0.f, 0.f, 0.f, 0.f);
            float4 vb = make_float4(0.f, 0.f, 0.f, 0.f);
            if (kk < EE) {                 // EE%4==0, full float4 when kk<EE
                va = *(const float4*)(emb + (size_t)toks[row] * EE + kk);
                vb = *(const float4*)(W + (size_t)(n0 + row) * EE + kk);
            }
            As[kc + 0][row] = va.x; As[kc + 1][row] = va.y;
            As[kc + 2][row] = va.z; As[kc + 3][row] = va.w;
            Bs[kc + 0][row] = vb.x; Bs[kc + 1][row] = vb.y;
            Bs[kc + 2][row] = vb.z; Bs[kc + 3][row] = vb.w;
        }
        __syncthreads();
#pragma unroll
        for (int k = 0; k < 16; ++k) {
            float a[8], bb[8];
#pragma unroll
            for (int i = 0; i < 8; ++i) a[i] = As[k][ty * 8 + i];
#pragma unroll
            for (int j = 0; j < 8; ++j) bb[j] = Bs[k][tx * 8 + j];
#pragma unroll
            for (int i = 0; i < 8; ++i)
#pragma unroll
                for (int j = 0; j < 8; ++j) acc[i][j] += a[i] * bb[j];
        }
        __syncthreads();
    }
    float bias[8];
#pragma unroll
    for (int j = 0; j < 8; ++j) {
        int col = n0 + tx * 8 + j;
        bias[j] = b1[col] + b2[col];
    }
#pragma unroll
    for (int i = 0; i < 8; ++i) {
        int row = m0 + ty * 8 + i;
        h8_t v;
#pragma unroll
        for (int j = 0; j < 8; ++j) v[j] = (_Float16)(acc[i][j] + bias[j]);
        *(h8_t*)(C + (size_t)row * GG + n0 + tx * 8) = v;
    }
}

// ---------------- layer-1 GEMM: A = hs chunk (f16, Mx1024), W f32 (2048x1024) ----------------
__global__ __launch_bounds__(256) void gemm_l1_kernel(const _Float16* __restrict__ A,
                                                      const float* __restrict__ W,
                                                      const float* __restrict__ b1,
                                                      const float* __restrict__ b2,
                                                      _Float16* __restrict__ C) {
    __shared__ float As[16][132];
    __shared__ float Bs[16][132];
    const int tid = threadIdx.x;
    const int m0 = blockIdx.y * 128, n0 = blockIdx.x * 128;
    const int ty = tid >> 4, tx = tid & 15;
    const int K = 2 * HH;   // 1024
    float acc[8][8];
#pragma unroll
    for (int i = 0; i < 8; ++i)
#pragma unroll
        for (int j = 0; j < 8; ++j) acc[i][j] = 0.0f;

    for (int k0 = 0; k0 < K; k0 += 16) {
        {   // A tile: 128 rows x 16 halfs; 256 threads x 1 h8 each
            int row = tid >> 1;
            int kc = (tid & 1) << 3;
            h8_t va = *(const h8_t*)(A + (size_t)(m0 + row) * K + k0 + kc);
#pragma unroll
            for (int j = 0; j < 8; ++j) As[kc + j][row] = (float)va[j];
        }
#pragma unroll
        for (int r = 0; r < 2; ++r) {  // B tile: 128 rows x 16 floats
            int idx = tid + r * 256;
            int row = idx >> 2;
            int kc = (idx & 3) << 2;
            float4 vb = *(const float4*)(W + (size_t)(n0 + row) * K + k0 + kc);
            Bs[kc + 0][row] = vb.x; Bs[kc + 1][row] = vb.y;
            Bs[kc + 2][row] = vb.z; Bs[kc + 3][row] = vb.w;
        }
        __syncthreads();
#pragma unroll
        for (int k = 0; k < 16; ++k) {
            float a[8], bb[8];
#pragma unroll
            for (int i = 0; i < 8; ++i) a[i] = As[k][ty * 8 + i];
#pragma unroll
            for (int j = 0; j < 8; ++j) bb[j] = Bs[k][tx * 8 + j];
#pragma unroll
            for (int i = 0; i < 8; ++i)
#pragma unroll
                for (int j = 0; j < 8; ++j) acc[i][j] += a[i] * bb[j];
        }
        __syncthreads();
    }
    float bias[8];
#pragma unroll
    for (int j = 0; j < 8; ++j) {
        int col = n0 + tx * 8 + j;
        bias[j] = b1[col] + b2[col];
    }
#pragma unroll
    for (int i = 0; i < 8; ++i) {
        int row = m0 + ty * 8 + i;
        h8_t v;
#pragma unroll
        for (int j = 0; j < 8; ++j) v[j] = (_Float16)(acc[i][j] + bias[j]);
        *(h8_t*)(C + (size_t)row * GG + n0 + tx * 8) = v;
    }
}

// ---------------- LSTM recurrence (one chunk, both directions) ----------------
// grid (Bc, 2), 512 threads. h in LDS f16, c in regs. hs chunk-local f16 out.
__global__ __launch_bounds__(512) void lstm_rec_kernel(const _Float16* __restrict__ gxf,
                                                       const _Float16* __restrict__ gxr,
                                                       const _Float16* __restrict__ WTf,
                                                       const _Float16* __restrict__ WTr,
                                                       const int* __restrict__ seq_len,
                                                       int c0,
                                                       _Float16* __restrict__ hs) {
    const int b_loc = blockIdx.x;
    const int dir = blockIdx.y;
    const _Float16* gx = dir ? gxr : gxf;
    const _Float16* WT = dir ? WTr : WTf;
    const int sl = seq_len[c0 + b_loc];
    const int tid = threadIdx.x;   // 0..511

    __shared__ _Float16 hraw[HH];
    __shared__ float gl[GG];

    hraw[tid] = (_Float16)0.0f;
    float c = 0.0f;
    __syncthreads();

    const h8_t* wp = (const h8_t*)WT;
    const h2_t* hb = (const h2_t*)hraw;

    for (int s = 0; s < sl; ++s) {
        const int t = dir ? (sl - 1 - s) : s;
        float acc0 = 0.f, acc1 = 0.f, acc2 = 0.f, acc3 = 0.f;
#pragma unroll 4
        for (int k2 = 0; k2 < 256; ++k2) {
            h2_t hk = hb[k2];                       // LDS broadcast
            h8_t w = wp[(size_t)k2 * 512 + tid];    // coalesced 16B/lane from L2
            float hx = (float)hk[0], hy = (float)hk[1];
            acc0 += hx * (float)w[0] + hy * (float)w[1];
            acc1 += hx * (float)w[2] + hy * (float)w[3];
            acc2 += hx * (float)w[4] + hy * (float)w[5];
            acc3 += hx * (float)w[6] + hy * (float)w[7];
        }
        size_t base = ((size_t)(b_loc * TT + t)) * GG + tid * 4;
        h4_t gv = *(const h4_t*)(gx + base);
        gl[tid * 4 + 0] = acc0 + (float)gv[0];
        gl[tid * 4 + 1] = acc1 + (float)gv[1];
        gl[tid * 4 + 2] = acc2 + (float)gv[2];
        gl[tid * 4 + 3] = acc3 + (float)gv[3];
        __syncthreads();
        float ii = sigf(gl[tid]);
        float ff = sigf(gl[HH + tid]);
        float g2 = tanhf(gl[2 * HH + tid]);
        float oo = sigf(gl[3 * HH + tid]);
        c = ff * c + ii * g2;
        float h = oo * tanhf(c);
        hraw[tid] = (_Float16)h;
        hs[((size_t)(b_loc * TT + t) << 10) + (dir << 9) + tid] = (_Float16)h;
        __syncthreads();
    }
    for (int t = sl; t < TT; ++t)   // masked tail = 0
        hs[((size_t)(b_loc * TT + t) << 10) + (dir << 9) + tid] = (_Float16)0.0f;
}

// ---------------- emissions: emis[m,c] = hs[m,:] . fc_w[c,:] + fc_b[c] ----------------
__global__ __launch_bounds__(256) void emis_kernel(const _Float16* __restrict__ hs,
                                                   const float* __restrict__ fc_w,
                                                   const float* __restrict__ fc_b,
                                                   float* __restrict__ emis, int n) {
    int idx = blockIdx.x * 256 + threadIdx.x;
    if (idx >= n) return;
    int m = idx / NC, cc = idx % NC;
    const h8_t* a = (const h8_t*)(hs + (size_t)m * 1024);
    const float4* w = (const float4*)(fc_w + (size_t)cc * 1024);
    float s = 0.f;
#pragma unroll 4
    for (int k = 0; k < 128; ++k) {
        h8_t x = a[k];
        float4 y0 = w[2 * k], y1 = w[2 * k + 1];
        s += (float)x[0] * y0.x + (float)x[1] * y0.y + (float)x[2] * y0.z + (float)x[3] * y0.w;
        s += (float)x[4] * y1.x + (float)x[5] * y1.y + (float)x[6] * y1.z + (float)x[7] * y1.w;
    }
    emis[idx] = s + fc_b[cc];
}

// ---------------- CRF: Viterbi + NLL forward, one block per batch row ----------------
__global__ __launch_bounds__(64) void crf_kernel(const float* __restrict__ emis,
                                                 const int* __restrict__ seq_len,
                                                 const int* __restrict__ tags,
                                                 const float* __restrict__ trans,
                                                 unsigned char* __restrict__ bt,
                                                 float* __restrict__ out, int c0) {
    const int b_loc = blockIdx.x;
    const int b = c0 + b_loc;
    const int lane = threadIdx.x;
    __shared__ float tr[NC * NC];
    for (int i = lane; i < NC * NC; i += 64) tr[i] = trans[i];
    __syncthreads();
    const int sl = seq_len[b];
    const bool act = lane < NC;
    const int jj = act ? lane : 0;

    float vs = 0.0f;       // viterbi scores
    float ns = NEGV;       // nll forward scores

    for (int t = 0; t < sl; ++t) {
        float ej = act ? emis[(size_t)(b_loc * TT + t) * NC + lane] : 0.0f;
        float vmax = -1e30f, nmax = -1e30f;
        int varg = 0;
        float nsave[NC];
#pragma unroll
        for (int i = 0; i < NC; ++i) {
            float vi = __shfl(vs, i);
            float ni = __shfl(ns, i);
            float tij = tr[i * NC + jj];
            float cv = vi + tij;
            if (cv > vmax) { vmax = cv; varg = i; }   // first-max (strict >, ascending i)
            float cn = ni + tij;
            nsave[i] = cn;
            if (cn > nmax) nmax = cn;
        }
        float ssum = 0.f;
#pragma unroll
        for (int i = 0; i < NC; ++i) ssum += expf(nsave[i] - nmax);
        if (act) {
            vs = vmax + ej;
            ns = nmax + logf(ssum) + ej;
            bt[(size_t)(b_loc * TT + t) * NC + lane] = (unsigned char)varg;
        }
    }

    float finv = act ? vs + tr[lane * NC + STOP_TAG] : -1e30f;
    float finn = act ? ns + tr[lane * NC + STOP_TAG] : -1e30f;
    float vbest = -1e30f, fmax = -1e30f;
    int barg = 0;
#pragma unroll
    for (int j = 0; j < NC; ++j) {
        float v = __shfl(finv, j);
        if (v > vbest) { vbest = v; barg = j; }
        float n = __shfl(finn, j);
        if (n > fmax) fmax = n;
    }
    float fsum = 0.f;
#pragma unroll
    for (int j = 0; j < NC; ++j) fsum += expf(__shfl(finn, j) - fmax);
    float fwd = fmax + logf(fsum);

    float gsum = 0.f;
    for (int t = lane; t < sl; t += 64) {
        int tg = tags[b * TT + t];
        int pv = (t == 0) ? START_TAG : tags[b * TT + t - 1];
        gsum += emis[(size_t)(b_loc * TT + t) * NC + tg] + tr[pv * NC + tg];
    }
#pragma unroll
    for (int off = 32; off > 0; off >>= 1) gsum += __shfl_down(gsum, off);

    if (lane == 0) {
        float gold = gsum + tr[tags[b * TT + sl - 1] * NC + STOP_TAG];
        atomicAdd(out + MM, (fwd - gold) * (1.0f / (float)BB));
        int cur = barg;
        for (int l = sl - 1; l >= 0; --l) {
            out[b * TT + l] = (float)cur;
            if (l >= 1) cur = (int)bt[(size_t)(b_loc * TT + l) * NC + cur];
        }
    }
    for (int l = sl + lane; l < TT; l += 64) out[b * TT + l] = 0.0f;
}

// ---------------- launch ----------------
extern "C" void kernel_launch(void* const* d_in, const int* in_sizes, int n_in,
                              void* d_out, int out_size, void* d_ws, size_t ws_size,
                              hipStream_t stream) {
    (void)in_sizes; (void)n_in; (void)out_size;
    const int* tokens = (const int*)d_in[0];
    const int* seqlen = (const int*)d_in[1];
    const int* tags = (const int*)d_in[3];
    const float* emb = (const float*)d_in[4];
    const float* w_ih_l0  = (const float*)d_in[5];
    const float* w_hh_l0  = (const float*)d_in[6];
    const float* b_ih_l0  = (const float*)d_in[7];
    const float* b_hh_l0  = (const float*)d_in[8];
    const float* w_ih_l0r = (const float*)d_in[9];
    const float* w_hh_l0r = (const float*)d_in[10];
    const float* b_ih_l0r = (const float*)d_in[11];
    const float* b_hh_l0r = (const float*)d_in[12];
    const float* w_ih_l1  = (const float*)d_in[13];
    const float* w_hh_l1  = (const float*)d_in[14];
    const float* b_ih_l1  = (const float*)d_in[15];
    const float* b_hh_l1  = (const float*)d_in[16];
    const float* w_ih_l1r = (const float*)d_in[17];
    const float* w_hh_l1r = (const float*)d_in[18];
    const float* b_ih_l1r = (const float*)d_in[19];
    const float* b_hh_l1r = (const float*)d_in[20];
    const float* fc_w  = (const float*)d_in[21];
    const float* fc_b  = (const float*)d_in[22];
    const float* trans = (const float*)d_in[23];

    // ---- adaptive chunking: fit workspace ----
    // per-b bytes: gx 2*1MiB + hs 512KiB + emis 11264 + bt 2816
    const size_t per_b = 2u * 1048576u + 524288u + 11264u + 2816u;   // 2,635,520
    const size_t fixed = 4u * 2097152u;                              // WT packs
    int Bc = 128;
    while (Bc > 8 && fixed + per_b * (size_t)Bc > ws_size) Bc >>= 1;

    char* ws = (char*)d_ws;
    _Float16* WT0f = (_Float16*)(ws);
    _Float16* WT0r = (_Float16*)(ws + 2097152u);
    _Float16* WT1f = (_Float16*)(ws + 2u * 2097152u);
    _Float16* WT1r = (_Float16*)(ws + 3u * 2097152u);
    char* p = ws + fixed;
    _Float16* gxf = (_Float16*)p;              p += (size_t)Bc * 1048576u;
    _Float16* gxr = (_Float16*)p;              p += (size_t)Bc * 1048576u;
    _Float16* hs  = (_Float16*)p;              p += (size_t)Bc * 524288u;
    float* emis   = (float*)p;                 p += (size_t)Bc * 11264u;
    unsigned char* bt = (unsigned char*)p;
    float* out = (float*)d_out;   // pred as floats [0,MM), loss at [MM]

    zero_loss_kernel<<<1, 1, 0, stream>>>(out);
    pack_whh_kernel<<<2048, 256, 0, stream>>>(w_hh_l0,  WT0f);
    pack_whh_kernel<<<2048, 256, 0, stream>>>(w_hh_l0r, WT0r);
    pack_whh_kernel<<<2048, 256, 0, stream>>>(w_hh_l1,  WT1f);
    pack_whh_kernel<<<2048, 256, 0, stream>>>(w_hh_l1r, WT1r);

    const int nchunk = BB / Bc;
    for (int cidx = 0; cidx < nchunk; ++cidx) {
        const int c0 = cidx * Bc;
        dim3 gdim(GG / 128, Bc * 2);   // N-tiles x M-tiles (M = Bc*256)
        gemm_l0_kernel<<<gdim, 256, 0, stream>>>(tokens + c0 * TT, emb, w_ih_l0,  b_ih_l0,  b_hh_l0,  gxf);
        gemm_l0_kernel<<<gdim, 256, 0, stream>>>(tokens + c0 * TT, emb, w_ih_l0r, b_ih_l0r, b_hh_l0r, gxr);
        lstm_rec_kernel<<<dim3(Bc, 2), 512, 0, stream>>>(gxf, gxr, WT0f, WT0r, seqlen, c0, hs);
        gemm_l1_kernel<<<gdim, 256, 0, stream>>>(hs, w_ih_l1,  b_ih_l1,  b_hh_l1,  gxf);
        gemm_l1_kernel<<<gdim, 256, 0, stream>>>(hs, w_ih_l1r, b_ih_l1r, b_hh_l1r, gxr);
        lstm_rec_kernel<<<dim3(Bc, 2), 512, 0, stream>>>(gxf, gxr, WT1f, WT1r, seqlen, c0, hs);
        emis_kernel<<<(Bc * TT * NC + 255) / 256, 256, 0, stream>>>(hs, fc_w, fc_b, emis, Bc * TT * NC);
        crf_kernel<<<Bc, 64, 0, stream>>>(emis, seqlen, tags, trans, bt, out, c0);
    }
}

// Round 3
// 15889.752 us; speedup vs baseline: 1.4878x; 1.4878x over previous
//
#include <hip/hip_runtime.h>
#include <hip/hip_bf16.h>
#include <hip/hip_fp16.h>

// Problem constants
#define BB   128
#define TT   256
#define EE   300
#define HH   512
#define GG   2048            // 4*H gates
#define NC   11
#define MM   (BB*TT)         // 32768
#define START_TAG 9
#define STOP_TAG  10
#define NEGV (-100000.0f)

typedef _Float16 h2_t __attribute__((ext_vector_type(2)));
typedef _Float16 h4_t __attribute__((ext_vector_type(4)));
typedef _Float16 h8_t __attribute__((ext_vector_type(8)));
typedef float    f4_t __attribute__((ext_vector_type(4)));

__device__ __forceinline__ float sigf(float x) { return 1.0f / (1.0f + __expf(-x)); }

// ---------------- init: zero barrier counters + loss slot ----------------
__global__ void init_kernel(float* out, int* cnt) {
    int t = threadIdx.x;
    if (t == 0) out[MM] = 0.0f;
    if (t < 64) cnt[t] = 0;
}

// ---------------- zero hs (h8 granularity) ----------------
__global__ __launch_bounds__(256) void zero_hs_kernel(_Float16* hs) {
    size_t i = (size_t)blockIdx.x * 256 + threadIdx.x;
    ((h8_t*)hs)[i] = (h8_t)(_Float16)0.0f;   // grid sized exactly
}

// ---------------- layer-0 GEMM with fused embedding gather ----------------
__global__ __launch_bounds__(256) void gemm_l0_kernel(const int* __restrict__ tok,
                                                      const float* __restrict__ emb,
                                                      const float* __restrict__ W,
                                                      const float* __restrict__ b1,
                                                      const float* __restrict__ b2,
                                                      _Float16* __restrict__ C) {
    __shared__ float As[16][132];
    __shared__ float Bs[16][132];
    __shared__ int   toks[128];
    const int tid = threadIdx.x;
    const int m0 = blockIdx.y * 128, n0 = blockIdx.x * 128;
    if (tid < 128) toks[tid] = tok[m0 + tid];
    const int ty = tid >> 4, tx = tid & 15;
    float acc[8][8];
#pragma unroll
    for (int i = 0; i < 8; ++i)
#pragma unroll
        for (int j = 0; j < 8; ++j) acc[i][j] = 0.0f;
    __syncthreads();

    for (int k0 = 0; k0 < EE; k0 += 16) {
#pragma unroll
        for (int r = 0; r < 2; ++r) {
            int idx = tid + r * 256;
            int row = idx >> 2;
            int kc = (idx & 3) << 2;
            int kk = k0 + kc;
            float4 va = make_float4(0.f, 0.f, 0.f, 0.f);
            float4 vb = make_float4(0.f, 0.f, 0.f, 0.f);
            if (kk < EE) {
                va = *(const float4*)(emb + (size_t)toks[row] * EE + kk);
                vb = *(const float4*)(W + (size_t)(n0 + row) * EE + kk);
            }
            As[kc + 0][row] = va.x; As[kc + 1][row] = va.y;
            As[kc + 2][row] = va.z; As[kc + 3][row] = va.w;
            Bs[kc + 0][row] = vb.x; Bs[kc + 1][row] = vb.y;
            Bs[kc + 2][row] = vb.z; Bs[kc + 3][row] = vb.w;
        }
        __syncthreads();
#pragma unroll
        for (int k = 0; k < 16; ++k) {
            float a[8], bb[8];
#pragma unroll
            for (int i = 0; i < 8; ++i) a[i] = As[k][ty * 8 + i];
#pragma unroll
            for (int j = 0; j < 8; ++j) bb[j] = Bs[k][tx * 8 + j];
#pragma unroll
            for (int i = 0; i < 8; ++i)
#pragma unroll
                for (int j = 0; j < 8; ++j) acc[i][j] += a[i] * bb[j];
        }
        __syncthreads();
    }
    float bias[8];
#pragma unroll
    for (int j = 0; j < 8; ++j) {
        int col = n0 + tx * 8 + j;
        bias[j] = b1[col] + b2[col];
    }
#pragma unroll
    for (int i = 0; i < 8; ++i) {
        int row = m0 + ty * 8 + i;
        h8_t v;
#pragma unroll
        for (int j = 0; j < 8; ++j) v[j] = (_Float16)(acc[i][j] + bias[j]);
        *(h8_t*)(C + (size_t)row * GG + n0 + tx * 8) = v;
    }
}

// ---------------- layer-1 GEMM: A = hs (f16, Mx1024), W f32 (2048x1024) ----------------
__global__ __launch_bounds__(256) void gemm_l1_kernel(const _Float16* __restrict__ A,
                                                      const float* __restrict__ W,
                                                      const float* __restrict__ b1,
                                                      const float* __restrict__ b2,
                                                      _Float16* __restrict__ C) {
    __shared__ float As[16][132];
    __shared__ float Bs[16][132];
    const int tid = threadIdx.x;
    const int m0 = blockIdx.y * 128, n0 = blockIdx.x * 128;
    const int ty = tid >> 4, tx = tid & 15;
    const int K = 2 * HH;
    float acc[8][8];
#pragma unroll
    for (int i = 0; i < 8; ++i)
#pragma unroll
        for (int j = 0; j < 8; ++j) acc[i][j] = 0.0f;

    for (int k0 = 0; k0 < K; k0 += 16) {
        {
            int row = tid >> 1;
            int kc = (tid & 1) << 3;
            h8_t va = *(const h8_t*)(A + (size_t)(m0 + row) * K + k0 + kc);
#pragma unroll
            for (int j = 0; j < 8; ++j) As[kc + j][row] = (float)va[j];
        }
#pragma unroll
        for (int r = 0; r < 2; ++r) {
            int idx = tid + r * 256;
            int row = idx >> 2;
            int kc = (idx & 3) << 2;
            float4 vb = *(const float4*)(W + (size_t)(n0 + row) * K + k0 + kc);
            Bs[kc + 0][row] = vb.x; Bs[kc + 1][row] = vb.y;
            Bs[kc + 2][row] = vb.z; Bs[kc + 3][row] = vb.w;
        }
        __syncthreads();
#pragma unroll
        for (int k = 0; k < 16; ++k) {
            float a[8], bb[8];
#pragma unroll
            for (int i = 0; i < 8; ++i) a[i] = As[k][ty * 8 + i];
#pragma unroll
            for (int j = 0; j < 8; ++j) bb[j] = Bs[k][tx * 8 + j];
#pragma unroll
            for (int i = 0; i < 8; ++i)
#pragma unroll
                for (int j = 0; j < 8; ++j) acc[i][j] += a[i] * bb[j];
        }
        __syncthreads();
    }
    float bias[8];
#pragma unroll
    for (int j = 0; j < 8; ++j) {
        int col = n0 + tx * 8 + j;
        bias[j] = b1[col] + b2[col];
    }
#pragma unroll
    for (int i = 0; i < 8; ++i) {
        int row = m0 + ty * 8 + i;
        h8_t v;
#pragma unroll
        for (int j = 0; j < 8; ++j) v[j] = (_Float16)(acc[i][j] + bias[j]);
        *(h8_t*)(C + (size_t)row * GG + n0 + tx * 8) = v;
    }
}

// ============ weight-stationary persistent LSTM recurrence ============
// Grid: 2*nbg*16 WGs (dir x batch-group-of-32 x gate-slice-of-16-hidden), 256 threads.
// Each WG: 64KB LDS = its W_hh slice (64 gate rows x 512 k, f16, frag-packed).
// Per step: M=32(batch) x N=64(gates) x K=512 via mfma 16x16x32 f16; h (32x512 f16)
// exchanged via double-buffered global h-buf + 16-WG atomic barrier.
__device__ __forceinline__ void gbar(int* cnt, int target) {
    __threadfence();            // release: h stores visible device-wide
    __syncthreads();
    if (threadIdx.x == 0) {
        atomicAdd(cnt, 1);
        while (atomicAdd(cnt, 0) < target) __builtin_amdgcn_s_sleep(2);
    }
    __syncthreads();
    __threadfence();            // acquire: invalidate L1 before h reads
}

__global__ __launch_bounds__(256, 1) void lstm_rec2_kernel(
        const _Float16* __restrict__ gx_f, const _Float16* __restrict__ gx_r,
        const float* __restrict__ whh_f, const float* __restrict__ whh_r,
        const int* __restrict__ seqlen, int c0, int nbg,
        _Float16* __restrict__ hs, _Float16* __restrict__ hbuf, int* __restrict__ cnt) {
    extern __shared__ _Float16 Wlds[];   // [nt(4)][kc(16)][lane(64)][8]  = 64 KB

    const int wg = blockIdx.x;
    const int gs = wg & 15;
    const int grp = wg >> 4;                 // dir*nbg + bg
    const int bg = grp % nbg;
    const int dir = grp / nbg;
    const _Float16* gx = dir ? gx_r : gx_f;
    const float* W = dir ? whh_r : whh_f;
    int* myCnt = cnt + grp;
    _Float16* hb = hbuf + (size_t)grp * 2 * 16384;   // two 32x512 f16 bufs

    const int tid = threadIdx.x;
    const int wv = tid >> 6, lane = tid & 63;
    const int mt = wv & 1;                   // m-tile: rows mt*16..+16
    const int p  = wv >> 1;                  // n-pair: hidden sub-slice p*8..+8
    const int col = lane & 15, quad = lane >> 4;

    // ---- pack W slice into LDS (frag-major, conflict-free reads) ----
    for (int e = tid; e < 4096; e += 256) {
        int ln = e & 63, kc = (e >> 6) & 15, nt = e >> 10;
        int pp = nt >> 1;
        int n_in_pair = ((nt & 1) << 4) + (ln & 15);     // 0..31
        int gt = n_in_pair >> 3, jj = n_in_pair & 7;
        int R = gt * 512 + gs * 16 + pp * 8 + jj;        // global gate row
        int k = kc * 32 + (ln >> 4) * 8;
        const float4* src = (const float4*)(W + (size_t)R * 512 + k);
        float4 f0 = src[0], f1 = src[1];
        h8_t v;
        v[0] = (_Float16)f0.x; v[1] = (_Float16)f0.y; v[2] = (_Float16)f0.z; v[3] = (_Float16)f0.w;
        v[4] = (_Float16)f1.x; v[5] = (_Float16)f1.y; v[6] = (_Float16)f1.z; v[7] = (_Float16)f1.w;
        *(h8_t*)(Wlds + (size_t)e * 8) = v;
    }
    __syncthreads();

    // ---- per-thread row metadata ----
    const int maxsl = seqlen[c0 + bg * 32];
    int sl_r[4];
#pragma unroll
    for (int r = 0; r < 4; ++r) sl_r[r] = seqlen[c0 + bg * 32 + mt * 16 + quad * 4 + r];

    const int jglob = gs * 16 + p * 8 + (col & 7);
    const int hi = col >> 3;

    // ---- init h_{-1} = 0 in buf1 (this WG's j-slice) ----
    for (int e = tid; e < 512; e += 256)
        hb[16384 + (e >> 4) * 512 + gs * 16 + (e & 15)] = (_Float16)0.0f;
    gbar(myCnt, 16 * 1);

    float cst[4] = {0.f, 0.f, 0.f, 0.f};
    float hst[4] = {0.f, 0.f, 0.f, 0.f};

    for (int s = 0; s < maxsl; ++s) {
        const _Float16* hrd = hb + ((s + 1) & 1) * 16384;
        _Float16* hwr = hb + (s & 1) * 16384;

        f4_t acc0 = {0.f, 0.f, 0.f, 0.f};
        f4_t acc1 = {0.f, 0.f, 0.f, 0.f};
        const int arow = (mt * 16 + col) * 512 + quad * 8;
#pragma unroll 4
        for (int kc = 0; kc < 16; ++kc) {
            h8_t a  = *(const h8_t*)(hrd + arow + kc * 32);
            h8_t b0 = *(const h8_t*)(Wlds + (((p * 2 + 0) * 16 + kc) * 64 + lane) * 8);
            h8_t b1 = *(const h8_t*)(Wlds + (((p * 2 + 1) * 16 + kc) * 64 + lane) * 8);
            acc0 = __builtin_amdgcn_mfma_f32_16x16x32_f16(a, b0, acc0, 0, 0, 0);
            acc1 = __builtin_amdgcn_mfma_f32_16x16x32_f16(a, b1, acc1, 0, 0, 0);
        }

#pragma unroll
        for (int r = 0; r < 4; ++r) {
            const int m = mt * 16 + quad * 4 + r;
            const int b_loc = bg * 32 + m;
            const bool valid = (s < sl_r[r]);
            const int tm = dir ? (sl_r[r] - 1 - s) : s;
            float g0v = 0.f, g1v = 0.f;
            if (valid) {
                size_t base = ((size_t)(b_loc * TT + tm)) * GG;
                g0v = (float)gx[base + hi * 512 + jglob];          // i or f column
                g1v = (float)gx[base + 1024 + hi * 512 + jglob];   // g or o column
            }
            float a0 = acc0[r] + g0v;
            float a1 = acc1[r] + g1v;
            float x0 = __shfl_xor(a0, 8);
            float x1 = __shfl_xor(a1, 8);
            float gi = hi ? x0 : a0;
            float gf = hi ? a0 : x0;
            float gg2 = hi ? x1 : a1;
            float go = hi ? a1 : x1;
            if (valid) {
                float cn = sigf(gf) * cst[r] + sigf(gi) * tanhf(gg2);
                float hn = sigf(go) * tanhf(cn);
                cst[r] = cn;
                hst[r] = hn;
                if (!hi)
                    hs[((size_t)(b_loc * TT + tm) << 10) + (dir << 9) + jglob] = (_Float16)hn;
            }
            if (!hi) hwr[m * 512 + jglob] = (_Float16)hst[r];   // carry frozen rows too
        }
        if (s + 1 < maxsl) gbar(myCnt, 16 * (s + 2));
    }
}

// ---------------- emissions ----------------
__global__ __launch_bounds__(256) void emis_kernel(const _Float16* __restrict__ hs,
                                                   const float* __restrict__ fc_w,
                                                   const float* __restrict__ fc_b,
                                                   float* __restrict__ emis, int n) {
    int idx = blockIdx.x * 256 + threadIdx.x;
    if (idx >= n) return;
    int m = idx / NC, cc = idx % NC;
    const h8_t* a = (const h8_t*)(hs + (size_t)m * 1024);
    const float4* w = (const float4*)(fc_w + (size_t)cc * 1024);
    float s = 0.f;
#pragma unroll 4
    for (int k = 0; k < 128; ++k) {
        h8_t x = a[k];
        float4 y0 = w[2 * k], y1 = w[2 * k + 1];
        s += (float)x[0] * y0.x + (float)x[1] * y0.y + (float)x[2] * y0.z + (float)x[3] * y0.w;
        s += (float)x[4] * y1.x + (float)x[5] * y1.y + (float)x[6] * y1.z + (float)x[7] * y1.w;
    }
    emis[idx] = s + fc_b[cc];
}

// ---------------- CRF: Viterbi + NLL forward ----------------
__global__ __launch_bounds__(64) void crf_kernel(const float* __restrict__ emis,
                                                 const int* __restrict__ seq_len,
                                                 const int* __restrict__ tags,
                                                 const float* __restrict__ trans,
                                                 unsigned char* __restrict__ bt,
                                                 float* __restrict__ out, int c0) {
    const int b_loc = blockIdx.x;
    const int b = c0 + b_loc;
    const int lane = threadIdx.x;
    __shared__ float tr[NC * NC];
    for (int i = lane; i < NC * NC; i += 64) tr[i] = trans[i];
    __syncthreads();
    const int sl = seq_len[b];
    const bool act = lane < NC;
    const int jj = act ? lane : 0;

    float vs = 0.0f;
    float ns = NEGV;

    for (int t = 0; t < sl; ++t) {
        float ej = act ? emis[(size_t)(b_loc * TT + t) * NC + lane] : 0.0f;
        float vmax = -1e30f, nmax = -1e30f;
        int varg = 0;
        float nsave[NC];
#pragma unroll
        for (int i = 0; i < NC; ++i) {
            float vi = __shfl(vs, i);
            float ni = __shfl(ns, i);
            float tij = tr[i * NC + jj];
            float cv = vi + tij;
            if (cv > vmax) { vmax = cv; varg = i; }
            float cn = ni + tij;
            nsave[i] = cn;
            if (cn > nmax) nmax = cn;
        }
        float ssum = 0.f;
#pragma unroll
        for (int i = 0; i < NC; ++i) ssum += expf(nsave[i] - nmax);
        if (act) {
            vs = vmax + ej;
            ns = nmax + logf(ssum) + ej;
            bt[(size_t)(b_loc * TT + t) * NC + lane] = (unsigned char)varg;
        }
    }

    float finv = act ? vs + tr[lane * NC + STOP_TAG] : -1e30f;
    float finn = act ? ns + tr[lane * NC + STOP_TAG] : -1e30f;
    float vbest = -1e30f, fmax = -1e30f;
    int barg = 0;
#pragma unroll
    for (int j = 0; j < NC; ++j) {
        float v = __shfl(finv, j);
        if (v > vbest) { vbest = v; barg = j; }
        float n = __shfl(finn, j);
        if (n > fmax) fmax = n;
    }
    float fsum = 0.f;
#pragma unroll
    for (int j = 0; j < NC; ++j) fsum += expf(__shfl(finn, j) - fmax);
    float fwd = fmax + logf(fsum);

    float gsum = 0.f;
    for (int t = lane; t < sl; t += 64) {
        int tg = tags[b * TT + t];
        int pv = (t == 0) ? START_TAG : tags[b * TT + t - 1];
        gsum += emis[(size_t)(b_loc * TT + t) * NC + tg] + tr[pv * NC + tg];
    }
#pragma unroll
    for (int off = 32; off > 0; off >>= 1) gsum += __shfl_down(gsum, off);

    if (lane == 0) {
        float gold = gsum + tr[tags[b * TT + sl - 1] * NC + STOP_TAG];
        atomicAdd(out + MM, (fwd - gold) * (1.0f / (float)BB));
        int cur = barg;
        for (int l = sl - 1; l >= 0; --l) {
            out[b * TT + l] = (float)cur;
            if (l >= 1) cur = (int)bt[(size_t)(b_loc * TT + l) * NC + cur];
        }
    }
    for (int l = sl + lane; l < TT; l += 64) out[b * TT + l] = 0.0f;
}

// ---------------- launch ----------------
extern "C" void kernel_launch(void* const* d_in, const int* in_sizes, int n_in,
                              void* d_out, int out_size, void* d_ws, size_t ws_size,
                              hipStream_t stream) {
    (void)in_sizes; (void)n_in; (void)out_size;
    const int* tokens = (const int*)d_in[0];
    const int* seqlen = (const int*)d_in[1];
    const int* tags = (const int*)d_in[3];
    const float* emb = (const float*)d_in[4];
    const float* w_ih_l0  = (const float*)d_in[5];
    const float* w_hh_l0  = (const float*)d_in[6];
    const float* b_ih_l0  = (const float*)d_in[7];
    const float* b_hh_l0  = (const float*)d_in[8];
    const float* w_ih_l0r = (const float*)d_in[9];
    const float* w_hh_l0r = (const float*)d_in[10];
    const float* b_ih_l0r = (const float*)d_in[11];
    const float* b_hh_l0r = (const float*)d_in[12];
    const float* w_ih_l1  = (const float*)d_in[13];
    const float* w_hh_l1  = (const float*)d_in[14];
    const float* b_ih_l1  = (const float*)d_in[15];
    const float* b_hh_l1  = (const float*)d_in[16];
    const float* w_ih_l1r = (const float*)d_in[17];
    const float* w_hh_l1r = (const float*)d_in[18];
    const float* b_ih_l1r = (const float*)d_in[19];
    const float* b_hh_l1r = (const float*)d_in[20];
    const float* fc_w  = (const float*)d_in[21];
    const float* fc_b  = (const float*)d_in[22];
    const float* trans = (const float*)d_in[23];

    // ---- adaptive chunking ----
    const size_t per_b = 2u * 1048576u + 524288u + 11264u + 2816u;   // gx f/r + hs + emis + bt
    const size_t fixed = 1048576u;                                   // hbuf 512KB + cnt + pad
    int Bc = 128;
    while (Bc > 32 && fixed + per_b * (size_t)Bc > ws_size) Bc >>= 1;

    char* ws = (char*)d_ws;
    _Float16* hbuf = (_Float16*)ws;              // 8 groups x 2 x 32x512 f16 = 512KB
    int* cnt = (int*)(ws + 524288u);             // 64 ints
    char* p = ws + fixed;
    _Float16* gxf = (_Float16*)p;              p += (size_t)Bc * 1048576u;
    _Float16* gxr = (_Float16*)p;              p += (size_t)Bc * 1048576u;
    _Float16* hs  = (_Float16*)p;              p += (size_t)Bc * 524288u;
    float* emis   = (float*)p;                 p += (size_t)Bc * 11264u;
    unsigned char* bt = (unsigned char*)p;
    float* out = (float*)d_out;   // pred as floats [0,MM), loss at [MM]

    init_kernel<<<1, 64, 0, stream>>>(out, cnt);

    const int nbg = Bc / 32;
    const int nchunk = BB / Bc;
    for (int cidx = 0; cidx < nchunk; ++cidx) {
        const int c0 = cidx * Bc;
        dim3 gdim(GG / 128, Bc * 2);
        int* cnt_l0 = cnt + (cidx * 2 + 0) * 8;
        int* cnt_l1 = cnt + (cidx * 2 + 1) * 8;

        zero_hs_kernel<<<Bc * 128, 256, 0, stream>>>(hs);   // Bc*32768 h8 units
        gemm_l0_kernel<<<gdim, 256, 0, stream>>>(tokens + c0 * TT, emb, w_ih_l0,  b_ih_l0,  b_hh_l0,  gxf);
        gemm_l0_kernel<<<gdim, 256, 0, stream>>>(tokens + c0 * TT, emb, w_ih_l0r, b_ih_l0r, b_hh_l0r, gxr);
        lstm_rec2_kernel<<<2 * nbg * 16, 256, 65536, stream>>>(
            gxf, gxr, w_hh_l0, w_hh_l0r, seqlen, c0, nbg, hs, hbuf, cnt_l0);
        gemm_l1_kernel<<<gdim, 256, 0, stream>>>(hs, w_ih_l1,  b_ih_l1,  b_hh_l1,  gxf);
        gemm_l1_kernel<<<gdim, 256, 0, stream>>>(hs, w_ih_l1r, b_ih_l1r, b_hh_l1r, gxr);
        lstm_rec2_kernel<<<2 * nbg * 16, 256, 65536, stream>>>(
            gxf, gxr, w_hh_l1, w_hh_l1r, seqlen, c0, nbg, hs, hbuf, cnt_l1);
        emis_kernel<<<(Bc * TT * NC + 255) / 256, 256, 0, stream>>>(hs, fc_w, fc_b, emis, Bc * TT * NC);
        crf_kernel<<<Bc, 64, 0, stream>>>(emis, seqlen, tags, trans, bt, out, c0);
    }
}

// Round 4
// 10301.051 us; speedup vs baseline: 2.2951x; 1.5425x over previous
//
#include <hip/hip_runtime.h>
#include <hip/hip_bf16.h>
#include <hip/hip_fp16.h>

// Problem constants
#define BB   128
#define TT   256
#define EE   300
#define KP0  320             // E padded to mult of 64
#define HH   512
#define GG   2048            // 4*H gates
#define NC   11
#define MM   (BB*TT)         // 32768
#define START_TAG 9
#define STOP_TAG  10
#define NEGV (-100000.0f)

typedef _Float16 h2_t __attribute__((ext_vector_type(2)));
typedef _Float16 h4_t __attribute__((ext_vector_type(4)));
typedef _Float16 h8_t __attribute__((ext_vector_type(8)));
typedef float    f4_t __attribute__((ext_vector_type(4)));

__device__ __forceinline__ float sigf(float x) { return 1.0f / (1.0f + __expf(-x)); }

__device__ __forceinline__ void fence_rel_agent() {
#if defined(__has_builtin)
#if __has_builtin(__builtin_amdgcn_fence)
    __builtin_amdgcn_fence(__ATOMIC_RELEASE, "agent");
#else
    __threadfence();
#endif
#else
    __threadfence();
#endif
}
__device__ __forceinline__ void fence_acq_agent() {
#if defined(__has_builtin)
#if __has_builtin(__builtin_amdgcn_fence)
    __builtin_amdgcn_fence(__ATOMIC_ACQUIRE, "agent");
#else
    __threadfence();
#endif
#else
    __threadfence();
#endif
}

// ---------------- init: zero barrier counters + loss slot ----------------
__global__ void init_kernel(float* out, int* cnt) {
    int t = threadIdx.x;
    if (t == 0) out[MM] = 0.0f;
    if (t < 64) cnt[t] = 0;
}

// ---------------- f32 -> f16 convert with K-pad (4-wide) ----------------
// O[r][c] = c<K ? (f16)W[r][c] : 0, O row stride Kp
__global__ __launch_bounds__(256) void conv_pad_kernel(const float* __restrict__ W,
                                                       _Float16* __restrict__ O,
                                                       int K, int Kp4, int total4) {
    int idx = blockIdx.x * 256 + threadIdx.x;
    if (idx >= total4) return;
    int r = idx / Kp4, c4 = idx % Kp4, c = c4 * 4;
    h4_t v;
    if (c < K) {   // K%4==0 so full float4
        float4 f = *(const float4*)(W + (size_t)r * K + c);
        v[0] = (_Float16)f.x; v[1] = (_Float16)f.y; v[2] = (_Float16)f.z; v[3] = (_Float16)f.w;
    } else {
        v[0] = v[1] = v[2] = v[3] = (_Float16)0.0f;
    }
    *(h4_t*)(O + (size_t)r * (Kp4 * 4) + c) = v;
}

// ---------------- embedding gather -> f16 padded (4-wide) ----------------
__global__ __launch_bounds__(256) void embed16_kernel(const int* __restrict__ tok,
                                                      const float* __restrict__ emb,
                                                      _Float16* __restrict__ x0,
                                                      int total4) {
    int idx = blockIdx.x * 256 + threadIdx.x;
    if (idx >= total4) return;
    int m = idx / (KP0 / 4), c4 = idx % (KP0 / 4), c = c4 * 4;
    h4_t v;
    if (c < EE) {
        float4 f = *(const float4*)(emb + (size_t)tok[m] * EE + c);
        v[0] = (_Float16)f.x; v[1] = (_Float16)f.y; v[2] = (_Float16)f.z; v[3] = (_Float16)f.w;
    } else {
        v[0] = v[1] = v[2] = v[3] = (_Float16)0.0f;
    }
    *(h4_t*)(x0 + (size_t)m * KP0 + c) = v;
}

// ---------------- MFMA GEMM: C[m,n] = sum_k A[m,k]*W[n,k] + b1[n]+b2[n] ----------------
// A: MxKp f16 row-major; W: 2048xKp f16 row-major; C: Mx2048 f16. Kp % 64 == 0.
// 128x128 tile, BK=64, 256 thr (4 waves, 2x2), 4x4 16x16x32 mfma per wave.
#define LDA 72    // padded LDS row stride (f16)
__global__ __launch_bounds__(256) void gemm_bt_kernel(const _Float16* __restrict__ A,
                                                      const _Float16* __restrict__ Wf,
                                                      const float* __restrict__ b1,
                                                      const float* __restrict__ b2,
                                                      _Float16* __restrict__ C,
                                                      int Kp) {
    __shared__ __align__(16) char smem[36864];
    _Float16* As = (_Float16*)smem;             // [128][72]
    _Float16* Bs = (_Float16*)(smem + 18432);   // [128][72]
    const int tid = threadIdx.x;
    const int m0 = blockIdx.y * 128, n0 = blockIdx.x * 128;
    const int wv = tid >> 6, lane = tid & 63;
    const int wm = wv & 1, wn = wv >> 1;
    const int col = lane & 15, quad = lane >> 4;

    f4_t acc[4][4];
#pragma unroll
    for (int i = 0; i < 4; ++i)
#pragma unroll
        for (int j = 0; j < 4; ++j) acc[i][j] = (f4_t){0.f, 0.f, 0.f, 0.f};

    for (int k0 = 0; k0 < Kp; k0 += 64) {
#pragma unroll
        for (int cch = 0; cch < 4; ++cch) {
            int id = cch * 256 + tid;           // 0..1023
            int row = id >> 3, cc = id & 7;     // 128 rows x 8 chunks of 8 f16
            h8_t va = *(const h8_t*)(A + (size_t)(m0 + row) * Kp + k0 + cc * 8);
            h8_t vb = *(const h8_t*)(Wf + (size_t)(n0 + row) * Kp + k0 + cc * 8);
            *(h8_t*)(As + row * LDA + cc * 8) = va;
            *(h8_t*)(Bs + row * LDA + cc * 8) = vb;
        }
        __syncthreads();
#pragma unroll
        for (int kk = 0; kk < 2; ++kk) {
            h8_t af[4], bf[4];
#pragma unroll
            for (int i = 0; i < 4; ++i) {
                af[i] = *(const h8_t*)(As + (wm * 64 + i * 16 + col) * LDA + kk * 32 + quad * 8);
                bf[i] = *(const h8_t*)(Bs + (wn * 64 + i * 16 + col) * LDA + kk * 32 + quad * 8);
            }
#pragma unroll
            for (int mi = 0; mi < 4; ++mi)
#pragma unroll
                for (int ni = 0; ni < 4; ++ni)
                    acc[mi][ni] = __builtin_amdgcn_mfma_f32_16x16x32_f16(af[mi], bf[ni], acc[mi][ni], 0, 0, 0);
        }
        __syncthreads();
    }

    // epilogue: bias + f16, LDS transpose for coalesced stores
    _Float16* Ct = (_Float16*)smem;   // [128][136]
#pragma unroll
    for (int ni = 0; ni < 4; ++ni) {
        int n = n0 + wn * 64 + ni * 16 + col;
        float bias = b1[n] + b2[n];
#pragma unroll
        for (int mi = 0; mi < 4; ++mi) {
#pragma unroll
            for (int r = 0; r < 4; ++r) {
                int mrow = wm * 64 + mi * 16 + quad * 4 + r;
                Ct[mrow * 136 + wn * 64 + ni * 16 + col] = (_Float16)(acc[mi][ni][r] + bias);
            }
        }
    }
    __syncthreads();
    {
        int row = tid >> 1, half = tid & 1;
#pragma unroll
        for (int cc2 = 0; cc2 < 8; ++cc2) {
            h8_t v = *(const h8_t*)(Ct + row * 136 + half * 64 + cc2 * 8);
            *(h8_t*)(C + (size_t)(m0 + row) * GG + n0 + half * 64 + cc2 * 8) = v;
        }
    }
}

// ============ weight-stationary persistent LSTM recurrence ============
// Grid: 2*nbg*16 WGs, 256 thr. 64KB LDS = W_hh slice (64 gate rows x 512 k, f16).
// Per step: M=32 x N=64 x K=512 via mfma 16x16x32 f16; h exchanged via
// double-buffered global hbuf + per-group generation barrier.
__device__ __forceinline__ void gbar(int* cnt, int target) {
    fence_rel_agent();              // make h stores visible (wbl2)
    __syncthreads();
    if (threadIdx.x == 0) {
        __hip_atomic_fetch_add(cnt, 1, __ATOMIC_RELAXED, __HIP_MEMORY_SCOPE_AGENT);
        while (__hip_atomic_load(cnt, __ATOMIC_RELAXED, __HIP_MEMORY_SCOPE_AGENT) < target)
            __builtin_amdgcn_s_sleep(4);
    }
    __syncthreads();
    fence_acq_agent();              // invalidate stale cache before h reads
}

__global__ __launch_bounds__(256, 1) void lstm_rec2_kernel(
        const _Float16* __restrict__ gx_f, const _Float16* __restrict__ gx_r,
        const float* __restrict__ whh_f, const float* __restrict__ whh_r,
        const int* __restrict__ seqlen, int c0, int nbg,
        _Float16* __restrict__ hs, _Float16* __restrict__ hbuf, int* __restrict__ cnt) {
    extern __shared__ _Float16 Wlds[];   // [nt(4)][kc(16)][lane(64)][8] = 64 KB

    const int wg = blockIdx.x;
    const int gs = wg & 15;
    const int grp = wg >> 4;
    const int bg = grp % nbg;
    const int dir = grp / nbg;
    const _Float16* gx = dir ? gx_r : gx_f;
    const float* W = dir ? whh_r : whh_f;
    int* myCnt = cnt + grp;
    _Float16* hb = hbuf + (size_t)grp * 2 * 16384;

    const int tid = threadIdx.x;
    const int wv = tid >> 6, lane = tid & 63;
    const int mt = wv & 1;
    const int p  = wv >> 1;
    const int col = lane & 15, quad = lane >> 4;

    // ---- pack W slice into LDS ----
    for (int e = tid; e < 4096; e += 256) {
        int ln = e & 63, kc = (e >> 6) & 15, nt = e >> 10;
        int pp = nt >> 1;
        int n_in_pair = ((nt & 1) << 4) + (ln & 15);
        int gt = n_in_pair >> 3, jj = n_in_pair & 7;
        int R = gt * 512 + gs * 16 + pp * 8 + jj;
        int k = kc * 32 + (ln >> 4) * 8;
        const float4* src = (const float4*)(W + (size_t)R * 512 + k);
        float4 f0 = src[0], f1 = src[1];
        h8_t v;
        v[0] = (_Float16)f0.x; v[1] = (_Float16)f0.y; v[2] = (_Float16)f0.z; v[3] = (_Float16)f0.w;
        v[4] = (_Float16)f1.x; v[5] = (_Float16)f1.y; v[6] = (_Float16)f1.z; v[7] = (_Float16)f1.w;
        *(h8_t*)(Wlds + (size_t)e * 8) = v;
    }
    __syncthreads();

    const int maxsl = seqlen[c0 + bg * 32];
    int sl_r[4];
#pragma unroll
    for (int r = 0; r < 4; ++r) sl_r[r] = seqlen[c0 + bg * 32 + mt * 16 + quad * 4 + r];

    const int jglob = gs * 16 + p * 8 + (col & 7);
    const int hi = col >> 3;

    // ---- prefetch gx for step 0 ----
    _Float16 pg0[4], pg1[4];
#pragma unroll
    for (int r = 0; r < 4; ++r) {
        pg0[r] = (_Float16)0.0f; pg1[r] = (_Float16)0.0f;
        if (0 < sl_r[r]) {
            int tm = dir ? (sl_r[r] - 1) : 0;
            int b_loc = bg * 32 + mt * 16 + quad * 4 + r;
            size_t base = ((size_t)(b_loc * TT + tm)) * GG;
            pg0[r] = gx[base + hi * 512 + jglob];
            pg1[r] = gx[base + 1024 + hi * 512 + jglob];
        }
    }

    // ---- init h_{-1} = 0 in buf1 ----
    for (int e = tid; e < 512; e += 256)
        hb[16384 + (e >> 4) * 512 + gs * 16 + (e & 15)] = (_Float16)0.0f;
    gbar(myCnt, 16);

    float cst[4] = {0.f, 0.f, 0.f, 0.f};
    float hst[4] = {0.f, 0.f, 0.f, 0.f};

    for (int s = 0; s < maxsl; ++s) {
        const _Float16* hrd = hb + ((s + 1) & 1) * 16384;
        _Float16* hwr = hb + (s & 1) * 16384;

        f4_t acc0 = {0.f, 0.f, 0.f, 0.f};
        f4_t acc1 = {0.f, 0.f, 0.f, 0.f};
        const int arow = (mt * 16 + col) * 512 + quad * 8;
#pragma unroll 4
        for (int kc = 0; kc < 16; ++kc) {
            h8_t a  = *(const h8_t*)(hrd + arow + kc * 32);
            h8_t b0 = *(const h8_t*)(Wlds + (((p * 2 + 0) * 16 + kc) * 64 + lane) * 8);
            h8_t b1 = *(const h8_t*)(Wlds + (((p * 2 + 1) * 16 + kc) * 64 + lane) * 8);
            acc0 = __builtin_amdgcn_mfma_f32_16x16x32_f16(a, b0, acc0, 0, 0, 0);
            acc1 = __builtin_amdgcn_mfma_f32_16x16x32_f16(a, b1, acc1, 0, 0, 0);
        }

        // capture current gx, then prefetch next step (hides HBM latency in spin)
        float cg0[4], cg1[4];
#pragma unroll
        for (int r = 0; r < 4; ++r) { cg0[r] = (float)pg0[r]; cg1[r] = (float)pg1[r]; }
        {
            int sn = s + 1;
#pragma unroll
            for (int r = 0; r < 4; ++r) {
                pg0[r] = (_Float16)0.0f; pg1[r] = (_Float16)0.0f;
                if (sn < sl_r[r]) {
                    int tm = dir ? (sl_r[r] - 1 - sn) : sn;
                    int b_loc = bg * 32 + mt * 16 + quad * 4 + r;
                    size_t base = ((size_t)(b_loc * TT + tm)) * GG;
                    pg0[r] = gx[base + hi * 512 + jglob];
                    pg1[r] = gx[base + 1024 + hi * 512 + jglob];
                }
            }
        }

#pragma unroll
        for (int r = 0; r < 4; ++r) {
            const int m = mt * 16 + quad * 4 + r;
            const int b_loc = bg * 32 + m;
            const bool valid = (s < sl_r[r]);
            const int tm = dir ? (sl_r[r] - 1 - s) : s;
            float a0 = acc0[r] + cg0[r];
            float a1 = acc1[r] + cg1[r];
            float x0v = __shfl_xor(a0, 8);
            float x1v = __shfl_xor(a1, 8);
            float gi = hi ? x0v : a0;
            float gf = hi ? a0 : x0v;
            float gg2 = hi ? x1v : a1;
            float go = hi ? a1 : x1v;
            if (valid) {
                float cn = sigf(gf) * cst[r] + sigf(gi) * tanhf(gg2);
                float hn = sigf(go) * tanhf(cn);
                cst[r] = cn;
                hst[r] = hn;
                if (!hi)
                    hs[((size_t)(b_loc * TT + tm) << 10) + (dir << 9) + jglob] = (_Float16)hn;
            }
            if (!hi) hwr[m * 512 + jglob] = (_Float16)hst[r];
        }
        if (s + 1 < maxsl) gbar(myCnt, 16 * (s + 2));
    }
}

// ---------------- emissions ----------------
__global__ __launch_bounds__(256) void emis_kernel(const _Float16* __restrict__ hs,
                                                   const float* __restrict__ fc_w,
                                                   const float* __restrict__ fc_b,
                                                   float* __restrict__ emis, int n) {
    int idx = blockIdx.x * 256 + threadIdx.x;
    if (idx >= n) return;
    int m = idx / NC, cc = idx % NC;
    const h8_t* a = (const h8_t*)(hs + (size_t)m * 1024);
    const float4* w = (const float4*)(fc_w + (size_t)cc * 1024);
    float s = 0.f;
#pragma unroll 4
    for (int k = 0; k < 128; ++k) {
        h8_t x = a[k];
        float4 y0 = w[2 * k], y1 = w[2 * k + 1];
        s += (float)x[0] * y0.x + (float)x[1] * y0.y + (float)x[2] * y0.z + (float)x[3] * y0.w;
        s += (float)x[4] * y1.x + (float)x[5] * y1.y + (float)x[6] * y1.z + (float)x[7] * y1.w;
    }
    emis[idx] = s + fc_b[cc];
}

// ---------------- CRF: Viterbi + NLL forward ----------------
__global__ __launch_bounds__(64) void crf_kernel(const float* __restrict__ emis,
                                                 const int* __restrict__ seq_len,
                                                 const int* __restrict__ tags,
                                                 const float* __restrict__ trans,
                                                 unsigned char* __restrict__ bt,
                                                 float* __restrict__ out, int c0) {
    const int b_loc = blockIdx.x;
    const int b = c0 + b_loc;
    const int lane = threadIdx.x;
    __shared__ float tr[NC * NC];
    for (int i = lane; i < NC * NC; i += 64) tr[i] = trans[i];
    __syncthreads();
    const int sl = seq_len[b];
    const bool act = lane < NC;
    const int jj = act ? lane : 0;

    float vs = 0.0f;
    float ns = NEGV;

    for (int t = 0; t < sl; ++t) {
        float ej = act ? emis[(size_t)(b_loc * TT + t) * NC + lane] : 0.0f;
        float vmax = -1e30f, nmax = -1e30f;
        int varg = 0;
        float nsave[NC];
#pragma unroll
        for (int i = 0; i < NC; ++i) {
            float vi = __shfl(vs, i);
            float ni = __shfl(ns, i);
            float tij = tr[i * NC + jj];
            float cv = vi + tij;
            if (cv > vmax) { vmax = cv; varg = i; }
            float cn = ni + tij;
            nsave[i] = cn;
            if (cn > nmax) nmax = cn;
        }
        float ssum = 0.f;
#pragma unroll
        for (int i = 0; i < NC; ++i) ssum += expf(nsave[i] - nmax);
        if (act) {
            vs = vmax + ej;
            ns = nmax + logf(ssum) + ej;
            bt[(size_t)(b_loc * TT + t) * NC + lane] = (unsigned char)varg;
        }
    }

    float finv = act ? vs + tr[lane * NC + STOP_TAG] : -1e30f;
    float finn = act ? ns + tr[lane * NC + STOP_TAG] : -1e30f;
    float vbest = -1e30f, fmax = -1e30f;
    int barg = 0;
#pragma unroll
    for (int j = 0; j < NC; ++j) {
        float v = __shfl(finv, j);
        if (v > vbest) { vbest = v; barg = j; }
        float n = __shfl(finn, j);
        if (n > fmax) fmax = n;
    }
    float fsum = 0.f;
#pragma unroll
    for (int j = 0; j < NC; ++j) fsum += expf(__shfl(finn, j) - fmax);
    float fwd = fmax + logf(fsum);

    float gsum = 0.f;
    for (int t = lane; t < sl; t += 64) {
        int tg = tags[b * TT + t];
        int pv = (t == 0) ? START_TAG : tags[b * TT + t - 1];
        gsum += emis[(size_t)(b_loc * TT + t) * NC + tg] + tr[pv * NC + tg];
    }
#pragma unroll
    for (int off = 32; off > 0; off >>= 1) gsum += __shfl_down(gsum, off);

    if (lane == 0) {
        float gold = gsum + tr[tags[b * TT + sl - 1] * NC + STOP_TAG];
        atomicAdd(out + MM, (fwd - gold) * (1.0f / (float)BB));
        int cur = barg;
        for (int l = sl - 1; l >= 0; --l) {
            out[b * TT + l] = (float)cur;
            if (l >= 1) cur = (int)bt[(size_t)(b_loc * TT + l) * NC + cur];
        }
    }
    for (int l = sl + lane; l < TT; l += 64) out[b * TT + l] = 0.0f;
}

// ---------------- launch ----------------
extern "C" void kernel_launch(void* const* d_in, const int* in_sizes, int n_in,
                              void* d_out, int out_size, void* d_ws, size_t ws_size,
                              hipStream_t stream) {
    (void)in_sizes; (void)n_in; (void)out_size;
    const int* tokens = (const int*)d_in[0];
    const int* seqlen = (const int*)d_in[1];
    const int* tags = (const int*)d_in[3];
    const float* emb = (const float*)d_in[4];
    const float* w_ih_l0  = (const float*)d_in[5];
    const float* w_hh_l0  = (const float*)d_in[6];
    const float* b_ih_l0  = (const float*)d_in[7];
    const float* b_hh_l0  = (const float*)d_in[8];
    const float* w_ih_l0r = (const float*)d_in[9];
    const float* w_hh_l0r = (const float*)d_in[10];
    const float* b_ih_l0r = (const float*)d_in[11];
    const float* b_hh_l0r = (const float*)d_in[12];
    const float* w_ih_l1  = (const float*)d_in[13];
    const float* w_hh_l1  = (const float*)d_in[14];
    const float* b_ih_l1  = (const float*)d_in[15];
    const float* b_hh_l1  = (const float*)d_in[16];
    const float* w_ih_l1r = (const float*)d_in[17];
    const float* w_hh_l1r = (const float*)d_in[18];
    const float* b_ih_l1r = (const float*)d_in[19];
    const float* b_hh_l1r = (const float*)d_in[20];
    const float* fc_w  = (const float*)d_in[21];
    const float* fc_b  = (const float*)d_in[22];
    const float* trans = (const float*)d_in[23];

    // ---- workspace layout ----
    // fixed: hbuf 512KB | cnt 4KB | w0f 1.25MB | w0r 1.25MB | w1f 4MB | w1r 4MB
    // per-b: gxf 1MB + gxr 1MB + hs 512KB + x0f16 160KB + emis 11264 + bt 2816
    const size_t per_b = 2097152u + 524288u + 163840u + 11264u + 2816u;  // 2,799,360
    const size_t fixed = 524288u + 4096u + 2u * 1310720u + 2u * 4194304u;
    int Bc = 128;
    while (Bc > 32 && fixed + per_b * (size_t)Bc > ws_size) Bc >>= 1;

    char* ws = (char*)d_ws;
    _Float16* hbuf = (_Float16*)ws;
    int* cnt = (int*)(ws + 524288u);
    _Float16* w0f = (_Float16*)(ws + 528384u);
    _Float16* w0r = (_Float16*)(ws + 528384u + 1310720u);
    _Float16* w1f = (_Float16*)(ws + 528384u + 2u * 1310720u);
    _Float16* w1r = (_Float16*)(ws + 528384u + 2u * 1310720u + 4194304u);
    char* p = ws + fixed;
    _Float16* gxf   = (_Float16*)p;   p += (size_t)Bc * 1048576u;
    _Float16* gxr   = (_Float16*)p;   p += (size_t)Bc * 1048576u;
    _Float16* hs    = (_Float16*)p;   p += (size_t)Bc * 524288u;
    _Float16* x0f16 = (_Float16*)p;   p += (size_t)Bc * 163840u;
    float* emis     = (float*)p;      p += (size_t)Bc * 11264u;
    unsigned char* bt = (unsigned char*)p;
    float* out = (float*)d_out;   // pred as floats [0,MM), loss at [MM]

    init_kernel<<<1, 64, 0, stream>>>(out, cnt);
    // one-time weight converts
    conv_pad_kernel<<<(2048 * 80 + 255) / 256, 256, 0, stream>>>(w_ih_l0,  w0f, EE, 80, 2048 * 80);
    conv_pad_kernel<<<(2048 * 80 + 255) / 256, 256, 0, stream>>>(w_ih_l0r, w0r, EE, 80, 2048 * 80);
    conv_pad_kernel<<<(2048 * 256 + 255) / 256, 256, 0, stream>>>(w_ih_l1,  w1f, 1024, 256, 2048 * 256);
    conv_pad_kernel<<<(2048 * 256 + 255) / 256, 256, 0, stream>>>(w_ih_l1r, w1r, 1024, 256, 2048 * 256);

    const int nbg = Bc / 32;
    const int nchunk = BB / Bc;
    for (int cidx = 0; cidx < nchunk; ++cidx) {
        const int c0 = cidx * Bc;
        const int Mc = Bc * TT;
        dim3 gdim(GG / 128, Mc / 128);
        int* cnt_l0 = cnt + (cidx * 2 + 0) * 8;
        int* cnt_l1 = cnt + (cidx * 2 + 1) * 8;

        embed16_kernel<<<(Mc * 80 + 255) / 256, 256, 0, stream>>>(tokens + c0 * TT, emb, x0f16, Mc * 80);
        gemm_bt_kernel<<<gdim, 256, 0, stream>>>(x0f16, w0f, b_ih_l0,  b_hh_l0,  gxf, KP0);
        gemm_bt_kernel<<<gdim, 256, 0, stream>>>(x0f16, w0r, b_ih_l0r, b_hh_l0r, gxr, KP0);
        lstm_rec2_kernel<<<2 * nbg * 16, 256, 65536, stream>>>(
            gxf, gxr, w_hh_l0, w_hh_l0r, seqlen, c0, nbg, hs, hbuf, cnt_l0);
        gemm_bt_kernel<<<gdim, 256, 0, stream>>>(hs, w1f, b_ih_l1,  b_hh_l1,  gxf, 1024);
        gemm_bt_kernel<<<gdim, 256, 0, stream>>>(hs, w1r, b_ih_l1r, b_hh_l1r, gxr, 1024);
        lstm_rec2_kernel<<<2 * nbg * 16, 256, 65536, stream>>>(
            gxf, gxr, w_hh_l1, w_hh_l1r, seqlen, c0, nbg, hs, hbuf, cnt_l1);
        emis_kernel<<<(Mc * NC + 255) / 256, 256, 0, stream>>>(hs, fc_w, fc_b, emis, Mc * NC);
        crf_kernel<<<Bc, 64, 0, stream>>>(emis, seqlen, tags, trans, bt, out, c0);
    }
}

// Round 5
// 6169.946 us; speedup vs baseline: 3.8317x; 1.6696x over previous
//
#include <hip/hip_runtime.h>
#include <hip/hip_bf16.h>
#include <hip/hip_fp16.h>

// Problem constants
#define BB   128
#define TT   256
#define EE   300
#define KP0  320             // E padded to mult of 64
#define HH   512
#define GG   2048            // 4*H gates
#define NC   11
#define MM   (BB*TT)         // 32768
#define START_TAG 9
#define STOP_TAG  10
#define NEGV (-100000.0f)

typedef _Float16 h2_t __attribute__((ext_vector_type(2)));
typedef _Float16 h4_t __attribute__((ext_vector_type(4)));
typedef _Float16 h8_t __attribute__((ext_vector_type(8)));
typedef float    f4_t __attribute__((ext_vector_type(4)));

__device__ __forceinline__ float sigf(float x) { return 1.0f / (1.0f + __expf(-x)); }

// ---------------- init: zero flags + loss slot ----------------
__global__ __launch_bounds__(256) void init_kernel(float* out, int* flags) {
    int t = threadIdx.x;
    if (t == 0) out[MM] = 0.0f;
    for (int i = t; i < 1024; i += 256) flags[i] = 0;
}

// ---------------- f32 -> f16 convert with K-pad (4-wide) ----------------
__global__ __launch_bounds__(256) void conv_pad_kernel(const float* __restrict__ W,
                                                       _Float16* __restrict__ O,
                                                       int K, int Kp4, int total4) {
    int idx = blockIdx.x * 256 + threadIdx.x;
    if (idx >= total4) return;
    int r = idx / Kp4, c4 = idx % Kp4, c = c4 * 4;
    h4_t v;
    if (c < K) {
        float4 f = *(const float4*)(W + (size_t)r * K + c);
        v[0] = (_Float16)f.x; v[1] = (_Float16)f.y; v[2] = (_Float16)f.z; v[3] = (_Float16)f.w;
    } else {
        v[0] = v[1] = v[2] = v[3] = (_Float16)0.0f;
    }
    *(h4_t*)(O + (size_t)r * (Kp4 * 4) + c) = v;
}

// ---------------- embedding gather -> f16 padded ----------------
__global__ __launch_bounds__(256) void embed16_kernel(const int* __restrict__ tok,
                                                      const float* __restrict__ emb,
                                                      _Float16* __restrict__ x0,
                                                      int total4) {
    int idx = blockIdx.x * 256 + threadIdx.x;
    if (idx >= total4) return;
    int m = idx / (KP0 / 4), c4 = idx % (KP0 / 4), c = c4 * 4;
    h4_t v;
    if (c < EE) {
        float4 f = *(const float4*)(emb + (size_t)tok[m] * EE + c);
        v[0] = (_Float16)f.x; v[1] = (_Float16)f.y; v[2] = (_Float16)f.z; v[3] = (_Float16)f.w;
    } else {
        v[0] = v[1] = v[2] = v[3] = (_Float16)0.0f;
    }
    *(h4_t*)(x0 + (size_t)m * KP0 + c) = v;
}

// ---------------- MFMA GEMM: C[m,n] = sum_k A[m,k]*W[n,k] + b1[n]+b2[n] ----------------
#define LDA 72
__global__ __launch_bounds__(256) void gemm_bt_kernel(const _Float16* __restrict__ A,
                                                      const _Float16* __restrict__ Wf,
                                                      const float* __restrict__ b1,
                                                      const float* __restrict__ b2,
                                                      _Float16* __restrict__ C,
                                                      int Kp) {
    __shared__ __align__(16) char smem[36864];
    _Float16* As = (_Float16*)smem;             // [128][72]
    _Float16* Bs = (_Float16*)(smem + 18432);   // [128][72]
    const int tid = threadIdx.x;
    const int m0 = blockIdx.y * 128, n0 = blockIdx.x * 128;
    const int wv = tid >> 6, lane = tid & 63;
    const int wm = wv & 1, wn = wv >> 1;
    const int col = lane & 15, quad = lane >> 4;

    f4_t acc[4][4];
#pragma unroll
    for (int i = 0; i < 4; ++i)
#pragma unroll
        for (int j = 0; j < 4; ++j) acc[i][j] = (f4_t){0.f, 0.f, 0.f, 0.f};

    for (int k0 = 0; k0 < Kp; k0 += 64) {
#pragma unroll
        for (int cch = 0; cch < 4; ++cch) {
            int id = cch * 256 + tid;
            int row = id >> 3, cc = id & 7;
            h8_t va = *(const h8_t*)(A + (size_t)(m0 + row) * Kp + k0 + cc * 8);
            h8_t vb = *(const h8_t*)(Wf + (size_t)(n0 + row) * Kp + k0 + cc * 8);
            *(h8_t*)(As + row * LDA + cc * 8) = va;
            *(h8_t*)(Bs + row * LDA + cc * 8) = vb;
        }
        __syncthreads();
#pragma unroll
        for (int kk = 0; kk < 2; ++kk) {
            h8_t af[4], bf[4];
#pragma unroll
            for (int i = 0; i < 4; ++i) {
                af[i] = *(const h8_t*)(As + (wm * 64 + i * 16 + col) * LDA + kk * 32 + quad * 8);
                bf[i] = *(const h8_t*)(Bs + (wn * 64 + i * 16 + col) * LDA + kk * 32 + quad * 8);
            }
#pragma unroll
            for (int mi = 0; mi < 4; ++mi)
#pragma unroll
                for (int ni = 0; ni < 4; ++ni)
                    acc[mi][ni] = __builtin_amdgcn_mfma_f32_16x16x32_f16(af[mi], bf[ni], acc[mi][ni], 0, 0, 0);
        }
        __syncthreads();
    }

    _Float16* Ct = (_Float16*)smem;   // [128][136]
#pragma unroll
    for (int ni = 0; ni < 4; ++ni) {
        int n = n0 + wn * 64 + ni * 16 + col;
        float bias = b1[n] + b2[n];
#pragma unroll
        for (int mi = 0; mi < 4; ++mi) {
#pragma unroll
            for (int r = 0; r < 4; ++r) {
                int mrow = wm * 64 + mi * 16 + quad * 4 + r;
                Ct[mrow * 136 + wn * 64 + ni * 16 + col] = (_Float16)(acc[mi][ni][r] + bias);
            }
        }
    }
    __syncthreads();
    {
        int row = tid >> 1, half = tid & 1;
#pragma unroll
        for (int cc2 = 0; cc2 < 8; ++cc2) {
            h8_t v = *(const h8_t*)(Ct + row * 136 + half * 64 + cc2 * 8);
            *(h8_t*)(C + (size_t)(m0 + row) * GG + n0 + half * 64 + cc2 * 8) = v;
        }
    }
}

// ============ weight-stationary persistent LSTM recurrence (fence-free) ============
// Grid: 2*nbg*16 WGs, 256 thr. 64KB LDS = W_hh slice + 1KB h-stage.
// h exchanged via MALL write-through (sc0 sc1) global ops; per-WG epoch flags
// (distributed barrier, no RMW contention, no cache-maintenance fences).
__global__ __launch_bounds__(256, 1) void lstm_rec3_kernel(
        const _Float16* __restrict__ gx_f, const _Float16* __restrict__ gx_r,
        const float* __restrict__ whh_f, const float* __restrict__ whh_r,
        const int* __restrict__ seqlen, int c0, int nbg,
        _Float16* __restrict__ hs, _Float16* __restrict__ hbuf, int* __restrict__ flags) {
    extern __shared__ _Float16 Wlds[];                 // 64KB W + 1KB stage
    _Float16* hstage = Wlds + 32768;                   // [32][16]

    const int wg = blockIdx.x;
    const int gs = wg & 15;
    const int grp = wg >> 4;
    const int bg = grp % nbg;
    const int dir = grp / nbg;
    const _Float16* gx = dir ? gx_r : gx_f;
    const float* W = dir ? whh_r : whh_f;
    int* myFlags = flags + grp * 16;
    _Float16* hb = hbuf + (size_t)grp * 2 * 16384;

    const int tid = threadIdx.x;
    const int wv = tid >> 6, lane = tid & 63;
    const int mt = wv & 1;                   // m-tile (waves: (mt,p) in {0,1}^2)
    const int p  = wv >> 1;
    const int col = lane & 15, quad = lane >> 4;

    // ---- pack W slice into LDS (plain cached loads, one-time) ----
    for (int e = tid; e < 4096; e += 256) {
        int ln = e & 63, kc = (e >> 6) & 15, nt = e >> 10;
        int pp = nt >> 1;
        int n_in_pair = ((nt & 1) << 4) + (ln & 15);
        int gt = n_in_pair >> 3, jj = n_in_pair & 7;
        int R = gt * 512 + gs * 16 + pp * 8 + jj;
        int k = kc * 32 + (ln >> 4) * 8;
        const float4* src = (const float4*)(W + (size_t)R * 512 + k);
        float4 f0 = src[0], f1 = src[1];
        h8_t v;
        v[0] = (_Float16)f0.x; v[1] = (_Float16)f0.y; v[2] = (_Float16)f0.z; v[3] = (_Float16)f0.w;
        v[4] = (_Float16)f1.x; v[5] = (_Float16)f1.y; v[6] = (_Float16)f1.z; v[7] = (_Float16)f1.w;
        *(h8_t*)(Wlds + (size_t)e * 8) = v;
    }
    __syncthreads();

    const int maxsl = seqlen[c0 + bg * 32];
    int sl_r[4];
#pragma unroll
    for (int r = 0; r < 4; ++r) sl_r[r] = seqlen[c0 + bg * 32 + mt * 16 + quad * 4 + r];

    const int jglob = gs * 16 + p * 8 + (col & 7);
    const int hi = col >> 3;

    // ---- prefetch gx for step 0 (plain cached loads) ----
    _Float16 pg0[4], pg1[4];
#pragma unroll
    for (int r = 0; r < 4; ++r) {
        pg0[r] = (_Float16)0.0f; pg1[r] = (_Float16)0.0f;
        if (0 < sl_r[r]) {
            int tm = dir ? (sl_r[r] - 1) : 0;
            int b_loc = bg * 32 + mt * 16 + quad * 4 + r;
            size_t base = ((size_t)(b_loc * TT + tm)) * GG;
            pg0[r] = gx[base + hi * 512 + jglob];
            pg1[r] = gx[base + 1024 + hi * 512 + jglob];
        }
    }

    // ---- publish h_{-1} = 0 into buf1 (write-through) ----
    if (tid < 128) {
        int m = tid >> 2, q = tid & 3;
        unsigned long long z = 0ull;
        const _Float16* dst = hb + 16384 + m * 512 + gs * 16 + q * 4;
        asm volatile("global_store_dwordx2 %0, %1, off sc0 sc1" :: "v"(dst), "v"(z) : "memory");
    }
    asm volatile("s_waitcnt vmcnt(0)" ::: "memory");
    __syncthreads();
    if (tid == 0) {
        int one = 1;
        asm volatile("global_store_dword %0, %1, off sc0 sc1" :: "v"(myFlags + gs), "v"(one) : "memory");
    }

    float cst[4] = {0.f, 0.f, 0.f, 0.f};
    float hst[4] = {0.f, 0.f, 0.f, 0.f};

    for (int s = 0; s < maxsl; ++s) {
        // ---- wait: all 16 WGs published h_{s-1} (flags >= s+1) ----
        if (tid < 16) {
            const int* fp = myFlags + tid;
            int v;
            for (;;) {
                asm volatile("global_load_dword %0, %1, off sc0 sc1\n\ts_waitcnt vmcnt(0)"
                             : "=v"(v) : "v"(fp) : "memory");
                if (v >= s + 1) break;
                __builtin_amdgcn_s_sleep(1);
            }
        }
        __syncthreads();

        const _Float16* hrd = hb + ((s + 1) & 1) * 16384;
        _Float16* hwr = hb + (s & 1) * 16384;

        // ---- load A fragments (16 x dwordx4, MALL-bypass, one drain) ----
        h8_t a[16];
        const _Float16* ap = hrd + (mt * 16 + col) * 512 + quad * 8;
#pragma unroll
        for (int kc = 0; kc < 16; ++kc)
            asm volatile("global_load_dwordx4 %0, %1, off sc0 sc1"
                         : "=v"(a[kc]) : "v"(ap + kc * 32));
        asm volatile("s_waitcnt vmcnt(0)" ::: "memory");

        f4_t acc0 = {0.f, 0.f, 0.f, 0.f};
        f4_t acc1 = {0.f, 0.f, 0.f, 0.f};
#pragma unroll
        for (int kc = 0; kc < 16; ++kc) {
            h8_t b0 = *(const h8_t*)(Wlds + (((p * 2 + 0) * 16 + kc) * 64 + lane) * 8);
            h8_t b1 = *(const h8_t*)(Wlds + (((p * 2 + 1) * 16 + kc) * 64 + lane) * 8);
            acc0 = __builtin_amdgcn_mfma_f32_16x16x32_f16(a[kc], b0, acc0, 0, 0, 0);
            acc1 = __builtin_amdgcn_mfma_f32_16x16x32_f16(a[kc], b1, acc1, 0, 0, 0);
        }

        // capture current gx, prefetch next step
        float cg0[4], cg1[4];
#pragma unroll
        for (int r = 0; r < 4; ++r) { cg0[r] = (float)pg0[r]; cg1[r] = (float)pg1[r]; }
        {
            int sn = s + 1;
#pragma unroll
            for (int r = 0; r < 4; ++r) {
                pg0[r] = (_Float16)0.0f; pg1[r] = (_Float16)0.0f;
                if (sn < sl_r[r]) {
                    int tm = dir ? (sl_r[r] - 1 - sn) : sn;
                    int b_loc = bg * 32 + mt * 16 + quad * 4 + r;
                    size_t base = ((size_t)(b_loc * TT + tm)) * GG;
                    pg0[r] = gx[base + hi * 512 + jglob];
                    pg1[r] = gx[base + 1024 + hi * 512 + jglob];
                }
            }
        }

        // ---- gates + state update; stage h slice in LDS ----
#pragma unroll
        for (int r = 0; r < 4; ++r) {
            const bool valid = (s < sl_r[r]);
            float a0 = acc0[r] + cg0[r];
            float a1 = acc1[r] + cg1[r];
            float x0v = __shfl_xor(a0, 8);
            float x1v = __shfl_xor(a1, 8);
            float gi = hi ? x0v : a0;
            float gf = hi ? a0 : x0v;
            float gg2 = hi ? x1v : a1;
            float go = hi ? a1 : x1v;
            if (valid) {
                float cn = sigf(gf) * cst[r] + sigf(gi) * tanhf(gg2);
                cst[r] = cn;
                hst[r] = sigf(go) * tanhf(cn);
            }
            if (!hi)
                hstage[(mt * 16 + quad * 4 + r) * 16 + p * 8 + (col & 7)] = (_Float16)hst[r];
        }
        __syncthreads();

        // ---- cooperative write-through publish of h_s ----
        if (tid < 128) {
            int m = tid >> 2, q = tid & 3;
            unsigned long long v = *(const unsigned long long*)(hstage + m * 16 + q * 4);
            const _Float16* dst = hwr + m * 512 + gs * 16 + q * 4;
            asm volatile("global_store_dwordx2 %0, %1, off sc0 sc1" :: "v"(dst), "v"(v) : "memory");
        }
        asm volatile("s_waitcnt vmcnt(0)" ::: "memory");
        __syncthreads();
        if (tid == 0) {
            int fv = s + 2;
            asm volatile("global_store_dword %0, %1, off sc0 sc1" :: "v"(myFlags + gs), "v"(fv) : "memory");
        }

        // ---- hs output stores (plain, overlap next spin) ----
#pragma unroll
        for (int r = 0; r < 4; ++r) {
            const bool valid = (s < sl_r[r]);
            if (valid && !hi) {
                int b_loc = bg * 32 + mt * 16 + quad * 4 + r;
                int tm = dir ? (sl_r[r] - 1 - s) : s;
                hs[((size_t)(b_loc * TT + tm) << 10) + (dir << 9) + jglob] = (_Float16)hst[r];
            }
        }
    }
}

// ---------------- emissions ----------------
__global__ __launch_bounds__(256) void emis_kernel(const _Float16* __restrict__ hs,
                                                   const float* __restrict__ fc_w,
                                                   const float* __restrict__ fc_b,
                                                   float* __restrict__ emis, int n) {
    int idx = blockIdx.x * 256 + threadIdx.x;
    if (idx >= n) return;
    int m = idx / NC, cc = idx % NC;
    const h8_t* a = (const h8_t*)(hs + (size_t)m * 1024);
    const float4* w = (const float4*)(fc_w + (size_t)cc * 1024);
    float s = 0.f;
#pragma unroll 4
    for (int k = 0; k < 128; ++k) {
        h8_t x = a[k];
        float4 y0 = w[2 * k], y1 = w[2 * k + 1];
        s += (float)x[0] * y0.x + (float)x[1] * y0.y + (float)x[2] * y0.z + (float)x[3] * y0.w;
        s += (float)x[4] * y1.x + (float)x[5] * y1.y + (float)x[6] * y1.z + (float)x[7] * y1.w;
    }
    emis[idx] = s + fc_b[cc];
}

// ---------------- CRF: Viterbi + NLL forward ----------------
__global__ __launch_bounds__(64) void crf_kernel(const float* __restrict__ emis,
                                                 const int* __restrict__ seq_len,
                                                 const int* __restrict__ tags,
                                                 const float* __restrict__ trans,
                                                 unsigned char* __restrict__ bt,
                                                 float* __restrict__ out, int c0) {
    const int b_loc = blockIdx.x;
    const int b = c0 + b_loc;
    const int lane = threadIdx.x;
    __shared__ float tr[NC * NC];
    for (int i = lane; i < NC * NC; i += 64) tr[i] = trans[i];
    __syncthreads();
    const int sl = seq_len[b];
    const bool act = lane < NC;
    const int jj = act ? lane : 0;

    float vs = 0.0f;
    float ns = NEGV;

    for (int t = 0; t < sl; ++t) {
        float ej = act ? emis[(size_t)(b_loc * TT + t) * NC + lane] : 0.0f;
        float vmax = -1e30f, nmax = -1e30f;
        int varg = 0;
        float nsave[NC];
#pragma unroll
        for (int i = 0; i < NC; ++i) {
            float vi = __shfl(vs, i);
            float ni = __shfl(ns, i);
            float tij = tr[i * NC + jj];
            float cv = vi + tij;
            if (cv > vmax) { vmax = cv; varg = i; }
            float cn = ni + tij;
            nsave[i] = cn;
            if (cn > nmax) nmax = cn;
        }
        float ssum = 0.f;
#pragma unroll
        for (int i = 0; i < NC; ++i) ssum += expf(nsave[i] - nmax);
        if (act) {
            vs = vmax + ej;
            ns = nmax + logf(ssum) + ej;
            bt[(size_t)(b_loc * TT + t) * NC + lane] = (unsigned char)varg;
        }
    }

    float finv = act ? vs + tr[lane * NC + STOP_TAG] : -1e30f;
    float finn = act ? ns + tr[lane * NC + STOP_TAG] : -1e30f;
    float vbest = -1e30f, fmax = -1e30f;
    int barg = 0;
#pragma unroll
    for (int j = 0; j < NC; ++j) {
        float v = __shfl(finv, j);
        if (v > vbest) { vbest = v; barg = j; }
        float n = __shfl(finn, j);
        if (n > fmax) fmax = n;
    }
    float fsum = 0.f;
#pragma unroll
    for (int j = 0; j < NC; ++j) fsum += expf(__shfl(finn, j) - fmax);
    float fwd = fmax + logf(fsum);

    float gsum = 0.f;
    for (int t = lane; t < sl; t += 64) {
        int tg = tags[b * TT + t];
        int pv = (t == 0) ? START_TAG : tags[b * TT + t - 1];
        gsum += emis[(size_t)(b_loc * TT + t) * NC + tg] + tr[pv * NC + tg];
    }
#pragma unroll
    for (int off = 32; off > 0; off >>= 1) gsum += __shfl_down(gsum, off);

    if (lane == 0) {
        float gold = gsum + tr[tags[b * TT + sl - 1] * NC + STOP_TAG];
        atomicAdd(out + MM, (fwd - gold) * (1.0f / (float)BB));
        int cur = barg;
        for (int l = sl - 1; l >= 0; --l) {
            out[b * TT + l] = (float)cur;
            if (l >= 1) cur = (int)bt[(size_t)(b_loc * TT + l) * NC + cur];
        }
    }
    for (int l = sl + lane; l < TT; l += 64) out[b * TT + l] = 0.0f;
}

// ---------------- launch ----------------
extern "C" void kernel_launch(void* const* d_in, const int* in_sizes, int n_in,
                              void* d_out, int out_size, void* d_ws, size_t ws_size,
                              hipStream_t stream) {
    (void)in_sizes; (void)n_in; (void)out_size;
    const int* tokens = (const int*)d_in[0];
    const int* seqlen = (const int*)d_in[1];
    const int* tags = (const int*)d_in[3];
    const float* emb = (const float*)d_in[4];
    const float* w_ih_l0  = (const float*)d_in[5];
    const float* w_hh_l0  = (const float*)d_in[6];
    const float* b_ih_l0  = (const float*)d_in[7];
    const float* b_hh_l0  = (const float*)d_in[8];
    const float* w_ih_l0r = (const float*)d_in[9];
    const float* w_hh_l0r = (const float*)d_in[10];
    const float* b_ih_l0r = (const float*)d_in[11];
    const float* b_hh_l0r = (const float*)d_in[12];
    const float* w_ih_l1  = (const float*)d_in[13];
    const float* w_hh_l1  = (const float*)d_in[14];
    const float* b_ih_l1  = (const float*)d_in[15];
    const float* b_hh_l1  = (const float*)d_in[16];
    const float* w_ih_l1r = (const float*)d_in[17];
    const float* w_hh_l1r = (const float*)d_in[18];
    const float* b_ih_l1r = (const float*)d_in[19];
    const float* b_hh_l1r = (const float*)d_in[20];
    const float* fc_w  = (const float*)d_in[21];
    const float* fc_b  = (const float*)d_in[22];
    const float* trans = (const float*)d_in[23];

    // ---- workspace layout ----
    const size_t per_b = 2097152u + 524288u + 163840u + 11264u + 2816u;  // 2,799,360
    const size_t fixed = 524288u + 4096u + 2u * 1310720u + 2u * 4194304u;
    int Bc = 128;
    while (Bc > 32 && fixed + per_b * (size_t)Bc > ws_size) Bc >>= 1;

    char* ws = (char*)d_ws;
    _Float16* hbuf = (_Float16*)ws;               // 8 grp x 2 x 32x512 f16
    int* flags = (int*)(ws + 524288u);            // 1024 ints
    _Float16* w0f = (_Float16*)(ws + 528384u);
    _Float16* w0r = (_Float16*)(ws + 528384u + 1310720u);
    _Float16* w1f = (_Float16*)(ws + 528384u + 2u * 1310720u);
    _Float16* w1r = (_Float16*)(ws + 528384u + 2u * 1310720u + 4194304u);
    char* p = ws + fixed;
    _Float16* gxf   = (_Float16*)p;   p += (size_t)Bc * 1048576u;
    _Float16* gxr   = (_Float16*)p;   p += (size_t)Bc * 1048576u;
    _Float16* hs    = (_Float16*)p;   p += (size_t)Bc * 524288u;
    _Float16* x0f16 = (_Float16*)p;   p += (size_t)Bc * 163840u;
    float* emis     = (float*)p;      p += (size_t)Bc * 11264u;
    unsigned char* bt = (unsigned char*)p;
    float* out = (float*)d_out;   // pred as floats [0,MM), loss at [MM]

    init_kernel<<<1, 256, 0, stream>>>(out, flags);
    conv_pad_kernel<<<(2048 * 80 + 255) / 256, 256, 0, stream>>>(w_ih_l0,  w0f, EE, 80, 2048 * 80);
    conv_pad_kernel<<<(2048 * 80 + 255) / 256, 256, 0, stream>>>(w_ih_l0r, w0r, EE, 80, 2048 * 80);
    conv_pad_kernel<<<(2048 * 256 + 255) / 256, 256, 0, stream>>>(w_ih_l1,  w1f, 1024, 256, 2048 * 256);
    conv_pad_kernel<<<(2048 * 256 + 255) / 256, 256, 0, stream>>>(w_ih_l1r, w1r, 1024, 256, 2048 * 256);

    const int nbg = Bc / 32;
    const int nchunk = BB / Bc;
    for (int cidx = 0; cidx < nchunk; ++cidx) {
        const int c0 = cidx * Bc;
        const int Mc = Bc * TT;
        dim3 gdim(GG / 128, Mc / 128);
        int* fl_l0 = flags + (cidx * 2 + 0) * 128;
        int* fl_l1 = flags + (cidx * 2 + 1) * 128;

        embed16_kernel<<<(Mc * 80 + 255) / 256, 256, 0, stream>>>(tokens + c0 * TT, emb, x0f16, Mc * 80);
        gemm_bt_kernel<<<gdim, 256, 0, stream>>>(x0f16, w0f, b_ih_l0,  b_hh_l0,  gxf, KP0);
        gemm_bt_kernel<<<gdim, 256, 0, stream>>>(x0f16, w0r, b_ih_l0r, b_hh_l0r, gxr, KP0);
        lstm_rec3_kernel<<<2 * nbg * 16, 256, 66560, stream>>>(
            gxf, gxr, w_hh_l0, w_hh_l0r, seqlen, c0, nbg, hs, hbuf, fl_l0);
        gemm_bt_kernel<<<gdim, 256, 0, stream>>>(hs, w1f, b_ih_l1,  b_hh_l1,  gxf, 1024);
        gemm_bt_kernel<<<gdim, 256, 0, stream>>>(hs, w1r, b_ih_l1r, b_hh_l1r, gxr, 1024);
        lstm_rec3_kernel<<<2 * nbg * 16, 256, 66560, stream>>>(
            gxf, gxr, w_hh_l1, w_hh_l1r, seqlen, c0, nbg, hs, hbuf, fl_l1);
        emis_kernel<<<(Mc * NC + 255) / 256, 256, 0, stream>>>(hs, fc_w, fc_b, emis, Mc * NC);
        crf_kernel<<<Bc, 64, 0, stream>>>(emis, seqlen, tags, trans, bt, out, c0);
    }
}

// Round 6
// 5761.147 us; speedup vs baseline: 4.1036x; 1.0710x over previous
//
#include <hip/hip_runtime.h>
#include <hip/hip_bf16.h>
#include <hip/hip_fp16.h>

// Problem constants
#define BB   128
#define TT   256
#define EE   300
#define KP0  320             // E padded to mult of 64
#define HH   512
#define GG   2048            // 4*H gates
#define NC   11
#define MM   (BB*TT)         // 32768
#define START_TAG 9
#define STOP_TAG  10
#define NEGV (-100000.0f)

typedef _Float16 h2_t __attribute__((ext_vector_type(2)));
typedef _Float16 h4_t __attribute__((ext_vector_type(4)));
typedef _Float16 h8_t __attribute__((ext_vector_type(8)));
typedef float    f4_t __attribute__((ext_vector_type(4)));

__device__ __forceinline__ float sigf(float x) { return 1.0f / (1.0f + __expf(-x)); }

// ---------------- init: zero flags + loss slot ----------------
__global__ __launch_bounds__(256) void init_kernel(float* out, int* flags) {
    int t = threadIdx.x;
    if (t == 0) out[MM] = 0.0f;
    for (int i = t; i < 1024; i += 256) flags[i] = 0;
}

// ---------------- f32 -> f16 convert with K-pad (4-wide) ----------------
__global__ __launch_bounds__(256) void conv_pad_kernel(const float* __restrict__ W,
                                                       _Float16* __restrict__ O,
                                                       int K, int Kp4, int total4) {
    int idx = blockIdx.x * 256 + threadIdx.x;
    if (idx >= total4) return;
    int r = idx / Kp4, c4 = idx % Kp4, c = c4 * 4;
    h4_t v;
    if (c < K) {
        float4 f = *(const float4*)(W + (size_t)r * K + c);
        v[0] = (_Float16)f.x; v[1] = (_Float16)f.y; v[2] = (_Float16)f.z; v[3] = (_Float16)f.w;
    } else {
        v[0] = v[1] = v[2] = v[3] = (_Float16)0.0f;
    }
    *(h4_t*)(O + (size_t)r * (Kp4 * 4) + c) = v;
}

// ---------------- embedding gather -> f16 padded ----------------
__global__ __launch_bounds__(256) void embed16_kernel(const int* __restrict__ tok,
                                                      const float* __restrict__ emb,
                                                      _Float16* __restrict__ x0,
                                                      int total4) {
    int idx = blockIdx.x * 256 + threadIdx.x;
    if (idx >= total4) return;
    int m = idx / (KP0 / 4), c4 = idx % (KP0 / 4), c = c4 * 4;
    h4_t v;
    if (c < EE) {
        float4 f = *(const float4*)(emb + (size_t)tok[m] * EE + c);
        v[0] = (_Float16)f.x; v[1] = (_Float16)f.y; v[2] = (_Float16)f.z; v[3] = (_Float16)f.w;
    } else {
        v[0] = v[1] = v[2] = v[3] = (_Float16)0.0f;
    }
    *(h4_t*)(x0 + (size_t)m * KP0 + c) = v;
}

// ---------------- MFMA GEMM: C[m,n] = sum_k A[m,k]*W[n,k] + b1[n]+b2[n] ----------------
#define LDA 72
__global__ __launch_bounds__(256) void gemm_bt_kernel(const _Float16* __restrict__ A,
                                                      const _Float16* __restrict__ Wf,
                                                      const float* __restrict__ b1,
                                                      const float* __restrict__ b2,
                                                      _Float16* __restrict__ C,
                                                      int Kp) {
    __shared__ __align__(16) char smem[36864];
    _Float16* As = (_Float16*)smem;             // [128][72]
    _Float16* Bs = (_Float16*)(smem + 18432);   // [128][72]
    const int tid = threadIdx.x;
    const int m0 = blockIdx.y * 128, n0 = blockIdx.x * 128;
    const int wv = tid >> 6, lane = tid & 63;
    const int wm = wv & 1, wn = wv >> 1;
    const int col = lane & 15, quad = lane >> 4;

    f4_t acc[4][4];
#pragma unroll
    for (int i = 0; i < 4; ++i)
#pragma unroll
        for (int j = 0; j < 4; ++j) acc[i][j] = (f4_t){0.f, 0.f, 0.f, 0.f};

    for (int k0 = 0; k0 < Kp; k0 += 64) {
#pragma unroll
        for (int cch = 0; cch < 4; ++cch) {
            int id = cch * 256 + tid;
            int row = id >> 3, cc = id & 7;
            h8_t va = *(const h8_t*)(A + (size_t)(m0 + row) * Kp + k0 + cc * 8);
            h8_t vb = *(const h8_t*)(Wf + (size_t)(n0 + row) * Kp + k0 + cc * 8);
            *(h8_t*)(As + row * LDA + cc * 8) = va;
            *(h8_t*)(Bs + row * LDA + cc * 8) = vb;
        }
        __syncthreads();
#pragma unroll
        for (int kk = 0; kk < 2; ++kk) {
            h8_t af[4], bf[4];
#pragma unroll
            for (int i = 0; i < 4; ++i) {
                af[i] = *(const h8_t*)(As + (wm * 64 + i * 16 + col) * LDA + kk * 32 + quad * 8);
                bf[i] = *(const h8_t*)(Bs + (wn * 64 + i * 16 + col) * LDA + kk * 32 + quad * 8);
            }
#pragma unroll
            for (int mi = 0; mi < 4; ++mi)
#pragma unroll
                for (int ni = 0; ni < 4; ++ni)
                    acc[mi][ni] = __builtin_amdgcn_mfma_f32_16x16x32_f16(af[mi], bf[ni], acc[mi][ni], 0, 0, 0);
        }
        __syncthreads();
    }

    _Float16* Ct = (_Float16*)smem;   // [128][136]
#pragma unroll
    for (int ni = 0; ni < 4; ++ni) {
        int n = n0 + wn * 64 + ni * 16 + col;
        float bias = b1[n] + b2[n];
#pragma unroll
        for (int mi = 0; mi < 4; ++mi) {
#pragma unroll
            for (int r = 0; r < 4; ++r) {
                int mrow = wm * 64 + mi * 16 + quad * 4 + r;
                Ct[mrow * 136 + wn * 64 + ni * 16 + col] = (_Float16)(acc[mi][ni][r] + bias);
            }
        }
    }
    __syncthreads();
    {
        int row = tid >> 1, half = tid & 1;
#pragma unroll
        for (int cc2 = 0; cc2 < 8; ++cc2) {
            h8_t v = *(const h8_t*)(Ct + row * 136 + half * 64 + cc2 * 8);
            *(h8_t*)(C + (size_t)(m0 + row) * GG + n0 + half * 64 + cc2 * 8) = v;
        }
    }
}

// ============ weight-stationary persistent LSTM recurrence (fence-free) ============
// Grid: 2*nbg*16 WGs, 256 thr. 64KB LDS = W_hh slice + 1KB h-stage.
// h exchanged via MALL write-through (sc0 sc1) global ops; per-WG epoch flags.
// Step-loop ordering keeps the publish->flag path free of HBM-latency ops:
// gx prefetch + hs output stores are issued AFTER the flag publish so their
// latency lands in the next step's poll shadow, not in the vmcnt(0) drain.
__global__ __launch_bounds__(256, 1) void lstm_rec3_kernel(
        const _Float16* __restrict__ gx_f, const _Float16* __restrict__ gx_r,
        const float* __restrict__ whh_f, const float* __restrict__ whh_r,
        const int* __restrict__ seqlen, int c0, int nbg,
        _Float16* __restrict__ hs, _Float16* __restrict__ hbuf, int* __restrict__ flags) {
    extern __shared__ _Float16 Wlds[];                 // 64KB W + 1KB stage
    _Float16* hstage = Wlds + 32768;                   // [32][16]

    const int wg = blockIdx.x;
    const int gs = wg & 15;
    const int grp = wg >> 4;
    const int bg = grp % nbg;
    const int dir = grp / nbg;
    const _Float16* gx = dir ? gx_r : gx_f;
    const float* W = dir ? whh_r : whh_f;
    int* myFlags = flags + grp * 16;
    _Float16* hb = hbuf + (size_t)grp * 2 * 16384;

    const int tid = threadIdx.x;
    const int wv = tid >> 6, lane = tid & 63;
    const int mt = wv & 1;
    const int p  = wv >> 1;
    const int col = lane & 15, quad = lane >> 4;

    // ---- pack W slice into LDS (one-time) ----
    for (int e = tid; e < 4096; e += 256) {
        int ln = e & 63, kc = (e >> 6) & 15, nt = e >> 10;
        int pp = nt >> 1;
        int n_in_pair = ((nt & 1) << 4) + (ln & 15);
        int gt = n_in_pair >> 3, jj = n_in_pair & 7;
        int R = gt * 512 + gs * 16 + pp * 8 + jj;
        int k = kc * 32 + (ln >> 4) * 8;
        const float4* src = (const float4*)(W + (size_t)R * 512 + k);
        float4 f0 = src[0], f1 = src[1];
        h8_t v;
        v[0] = (_Float16)f0.x; v[1] = (_Float16)f0.y; v[2] = (_Float16)f0.z; v[3] = (_Float16)f0.w;
        v[4] = (_Float16)f1.x; v[5] = (_Float16)f1.y; v[6] = (_Float16)f1.z; v[7] = (_Float16)f1.w;
        *(h8_t*)(Wlds + (size_t)e * 8) = v;
    }
    __syncthreads();

    const int maxsl = seqlen[c0 + bg * 32];
    int sl_r[4];
#pragma unroll
    for (int r = 0; r < 4; ++r) sl_r[r] = seqlen[c0 + bg * 32 + mt * 16 + quad * 4 + r];

    const int jglob = gs * 16 + p * 8 + (col & 7);
    const int hi = col >> 3;

    // ---- prefetch gx for step 0 ----
    _Float16 pg0[4], pg1[4];
#pragma unroll
    for (int r = 0; r < 4; ++r) {
        pg0[r] = (_Float16)0.0f; pg1[r] = (_Float16)0.0f;
        if (0 < sl_r[r]) {
            int tm = dir ? (sl_r[r] - 1) : 0;
            int b_loc = bg * 32 + mt * 16 + quad * 4 + r;
            size_t base = ((size_t)(b_loc * TT + tm)) * GG;
            pg0[r] = gx[base + hi * 512 + jglob];
            pg1[r] = gx[base + 1024 + hi * 512 + jglob];
        }
    }

    // ---- publish h_{-1} = 0 into buf1 (write-through) ----
    if (tid < 128) {
        int m = tid >> 2, q = tid & 3;
        unsigned long long z = 0ull;
        const _Float16* dst = hb + 16384 + m * 512 + gs * 16 + q * 4;
        asm volatile("global_store_dwordx2 %0, %1, off sc0 sc1" :: "v"(dst), "v"(z) : "memory");
    }
    asm volatile("s_waitcnt vmcnt(0)" ::: "memory");
    __syncthreads();
    if (tid == 0) {
        int one = 1;
        asm volatile("global_store_dword %0, %1, off sc0 sc1" :: "v"(myFlags + gs), "v"(one) : "memory");
    }

    float cst[4] = {0.f, 0.f, 0.f, 0.f};
    float hst[4] = {0.f, 0.f, 0.f, 0.f};

    for (int s = 0; s < maxsl; ++s) {
        // ---- wait: all 16 WGs published h_{s-1} (progressive backoff) ----
        if (tid < 16) {
            const int* fp = myFlags + tid;
            int v, it = 0;
            for (;;) {
                asm volatile("global_load_dword %0, %1, off sc0 sc1\n\ts_waitcnt vmcnt(0)"
                             : "=v"(v) : "v"(fp) : "memory");
                if (v >= s + 1) break;
                if (it < 3) __builtin_amdgcn_s_sleep(1);
                else        __builtin_amdgcn_s_sleep(4);
                ++it;
            }
        }
        __syncthreads();

        const _Float16* hrd = hb + ((s + 1) & 1) * 16384;
        _Float16* hwr = hb + (s & 1) * 16384;

        // ---- load A fragments (16 x dwordx4, MALL-bypass, one drain) ----
        h8_t a[16];
        const _Float16* ap = hrd + (mt * 16 + col) * 512 + quad * 8;
#pragma unroll
        for (int kc = 0; kc < 16; ++kc)
            asm volatile("global_load_dwordx4 %0, %1, off sc0 sc1"
                         : "=v"(a[kc]) : "v"(ap + kc * 32));
        asm volatile("s_waitcnt vmcnt(0)" ::: "memory");

        f4_t acc0 = {0.f, 0.f, 0.f, 0.f};
        f4_t acc1 = {0.f, 0.f, 0.f, 0.f};
#pragma unroll
        for (int kc = 0; kc < 16; ++kc) {
            h8_t b0 = *(const h8_t*)(Wlds + (((p * 2 + 0) * 16 + kc) * 64 + lane) * 8);
            h8_t b1 = *(const h8_t*)(Wlds + (((p * 2 + 1) * 16 + kc) * 64 + lane) * 8);
            acc0 = __builtin_amdgcn_mfma_f32_16x16x32_f16(a[kc], b0, acc0, 0, 0, 0);
            acc1 = __builtin_amdgcn_mfma_f32_16x16x32_f16(a[kc], b1, acc1, 0, 0, 0);
        }

        // ---- gates + state update (gx already in regs); stage h in LDS ----
#pragma unroll
        for (int r = 0; r < 4; ++r) {
            const bool valid = (s < sl_r[r]);
            float a0 = acc0[r] + (float)pg0[r];
            float a1 = acc1[r] + (float)pg1[r];
            float x0v = __shfl_xor(a0, 8);
            float x1v = __shfl_xor(a1, 8);
            float gi = hi ? x0v : a0;
            float gf = hi ? a0 : x0v;
            float gg2 = hi ? x1v : a1;
            float go = hi ? a1 : x1v;
            if (valid) {
                float cn = sigf(gf) * cst[r] + sigf(gi) * tanhf(gg2);
                cst[r] = cn;
                hst[r] = sigf(go) * tanhf(cn);
            }
            if (!hi)
                hstage[(mt * 16 + quad * 4 + r) * 16 + p * 8 + (col & 7)] = (_Float16)hst[r];
        }
        __syncthreads();

        // ---- cooperative write-through publish of h_s (clean drain: only
        //      these 128 stores are outstanding in the publishing waves) ----
        if (tid < 128) {
            int m = tid >> 2, q = tid & 3;
            unsigned long long v = *(const unsigned long long*)(hstage + m * 16 + q * 4);
            const _Float16* dst = hwr + m * 512 + gs * 16 + q * 4;
            asm volatile("global_store_dwordx2 %0, %1, off sc0 sc1" :: "v"(dst), "v"(v) : "memory");
        }
        asm volatile("s_waitcnt vmcnt(0)" ::: "memory");
        __syncthreads();
        if (tid == 0) {
            int fv = s + 2;
            asm volatile("global_store_dword %0, %1, off sc0 sc1" :: "v"(myFlags + gs), "v"(fv) : "memory");
        }

        // ---- post-flag shadow work: overlaps the next step's poll ----
        // hs output stores (plain, fire-and-forget)
#pragma unroll
        for (int r = 0; r < 4; ++r) {
            const bool valid = (s < sl_r[r]);
            if (valid && !hi) {
                int b_loc = bg * 32 + mt * 16 + quad * 4 + r;
                int tm = dir ? (sl_r[r] - 1 - s) : s;
                hs[((size_t)(b_loc * TT + tm) << 10) + (dir << 9) + jglob] = (_Float16)hst[r];
            }
        }
        // gx prefetch for step s+1 (HBM latency hides under next poll)
        {
            int sn = s + 1;
#pragma unroll
            for (int r = 0; r < 4; ++r) {
                pg0[r] = (_Float16)0.0f; pg1[r] = (_Float16)0.0f;
                if (sn < sl_r[r]) {
                    int tm = dir ? (sl_r[r] - 1 - sn) : sn;
                    int b_loc = bg * 32 + mt * 16 + quad * 4 + r;
                    size_t base = ((size_t)(b_loc * TT + tm)) * GG;
                    pg0[r] = gx[base + hi * 512 + jglob];
                    pg1[r] = gx[base + 1024 + hi * 512 + jglob];
                }
            }
        }
    }
}

// ---------------- emissions ----------------
__global__ __launch_bounds__(256) void emis_kernel(const _Float16* __restrict__ hs,
                                                   const float* __restrict__ fc_w,
                                                   const float* __restrict__ fc_b,
                                                   float* __restrict__ emis, int n) {
    int idx = blockIdx.x * 256 + threadIdx.x;
    if (idx >= n) return;
    int m = idx / NC, cc = idx % NC;
    const h8_t* a = (const h8_t*)(hs + (size_t)m * 1024);
    const float4* w = (const float4*)(fc_w + (size_t)cc * 1024);
    float s = 0.f;
#pragma unroll 4
    for (int k = 0; k < 128; ++k) {
        h8_t x = a[k];
        float4 y0 = w[2 * k], y1 = w[2 * k + 1];
        s += (float)x[0] * y0.x + (float)x[1] * y0.y + (float)x[2] * y0.z + (float)x[3] * y0.w;
        s += (float)x[4] * y1.x + (float)x[5] * y1.y + (float)x[6] * y1.z + (float)x[7] * y1.w;
    }
    emis[idx] = s + fc_b[cc];
}

// ---------------- CRF: Viterbi + NLL forward ----------------
__global__ __launch_bounds__(64) void crf_kernel(const float* __restrict__ emis,
                                                 const int* __restrict__ seq_len,
                                                 const int* __restrict__ tags,
                                                 const float* __restrict__ trans,
                                                 unsigned char* __restrict__ bt,
                                                 float* __restrict__ out, int c0) {
    const int b_loc = blockIdx.x;
    const int b = c0 + b_loc;
    const int lane = threadIdx.x;
    __shared__ float tr[NC * NC];
    for (int i = lane; i < NC * NC; i += 64) tr[i] = trans[i];
    __syncthreads();
    const int sl = seq_len[b];
    const bool act = lane < NC;
    const int jj = act ? lane : 0;

    float vs = 0.0f;
    float ns = NEGV;

    for (int t = 0; t < sl; ++t) {
        float ej = act ? emis[(size_t)(b_loc * TT + t) * NC + lane] : 0.0f;
        float vmax = -1e30f, nmax = -1e30f;
        int varg = 0;
        float nsave[NC];
#pragma unroll
        for (int i = 0; i < NC; ++i) {
            float vi = __shfl(vs, i);
            float ni = __shfl(ns, i);
            float tij = tr[i * NC + jj];
            float cv = vi + tij;
            if (cv > vmax) { vmax = cv; varg = i; }
            float cn = ni + tij;
            nsave[i] = cn;
            if (cn > nmax) nmax = cn;
        }
        float ssum = 0.f;
#pragma unroll
        for (int i = 0; i < NC; ++i) ssum += expf(nsave[i] - nmax);
        if (act) {
            vs = vmax + ej;
            ns = nmax + logf(ssum) + ej;
            bt[(size_t)(b_loc * TT + t) * NC + lane] = (unsigned char)varg;
        }
    }

    float finv = act ? vs + tr[lane * NC + STOP_TAG] : -1e30f;
    float finn = act ? ns + tr[lane * NC + STOP_TAG] : -1e30f;
    float vbest = -1e30f, fmax = -1e30f;
    int barg = 0;
#pragma unroll
    for (int j = 0; j < NC; ++j) {
        float v = __shfl(finv, j);
        if (v > vbest) { vbest = v; barg = j; }
        float n = __shfl(finn, j);
        if (n > fmax) fmax = n;
    }
    float fsum = 0.f;
#pragma unroll
    for (int j = 0; j < NC; ++j) fsum += expf(__shfl(finn, j) - fmax);
    float fwd = fmax + logf(fsum);

    float gsum = 0.f;
    for (int t = lane; t < sl; t += 64) {
        int tg = tags[b * TT + t];
        int pv = (t == 0) ? START_TAG : tags[b * TT + t - 1];
        gsum += emis[(size_t)(b_loc * TT + t) * NC + tg] + tr[pv * NC + tg];
    }
#pragma unroll
    for (int off = 32; off > 0; off >>= 1) gsum += __shfl_down(gsum, off);

    if (lane == 0) {
        float gold = gsum + tr[tags[b * TT + sl - 1] * NC + STOP_TAG];
        atomicAdd(out + MM, (fwd - gold) * (1.0f / (float)BB));
        int cur = barg;
        for (int l = sl - 1; l >= 0; --l) {
            out[b * TT + l] = (float)cur;
            if (l >= 1) cur = (int)bt[(size_t)(b_loc * TT + l) * NC + cur];
        }
    }
    for (int l = sl + lane; l < TT; l += 64) out[b * TT + l] = 0.0f;
}

// ---------------- launch ----------------
extern "C" void kernel_launch(void* const* d_in, const int* in_sizes, int n_in,
                              void* d_out, int out_size, void* d_ws, size_t ws_size,
                              hipStream_t stream) {
    (void)in_sizes; (void)n_in; (void)out_size;
    const int* tokens = (const int*)d_in[0];
    const int* seqlen = (const int*)d_in[1];
    const int* tags = (const int*)d_in[3];
    const float* emb = (const float*)d_in[4];
    const float* w_ih_l0  = (const float*)d_in[5];
    const float* w_hh_l0  = (const float*)d_in[6];
    const float* b_ih_l0  = (const float*)d_in[7];
    const float* b_hh_l0  = (const float*)d_in[8];
    const float* w_ih_l0r = (const float*)d_in[9];
    const float* w_hh_l0r = (const float*)d_in[10];
    const float* b_ih_l0r = (const float*)d_in[11];
    const float* b_hh_l0r = (const float*)d_in[12];
    const float* w_ih_l1  = (const float*)d_in[13];
    const float* w_hh_l1  = (const float*)d_in[14];
    const float* b_ih_l1  = (const float*)d_in[15];
    const float* b_hh_l1  = (const float*)d_in[16];
    const float* w_ih_l1r = (const float*)d_in[17];
    const float* w_hh_l1r = (const float*)d_in[18];
    const float* b_ih_l1r = (const float*)d_in[19];
    const float* b_hh_l1r = (const float*)d_in[20];
    const float* fc_w  = (const float*)d_in[21];
    const float* fc_b  = (const float*)d_in[22];
    const float* trans = (const float*)d_in[23];

    // ---- workspace layout ----
    const size_t per_b = 2097152u + 524288u + 163840u + 11264u + 2816u;  // 2,799,360
    const size_t fixed = 524288u + 4096u + 2u * 1310720u + 2u * 4194304u;
    int Bc = 128;
    while (Bc > 32 && fixed + per_b * (size_t)Bc > ws_size) Bc >>= 1;

    char* ws = (char*)d_ws;
    _Float16* hbuf = (_Float16*)ws;               // 8 grp x 2 x 32x512 f16
    int* flags = (int*)(ws + 524288u);            // 1024 ints
    _Float16* w0f = (_Float16*)(ws + 528384u);
    _Float16* w0r = (_Float16*)(ws + 528384u + 1310720u);
    _Float16* w1f = (_Float16*)(ws + 528384u + 2u * 1310720u);
    _Float16* w1r = (_Float16*)(ws + 528384u + 2u * 1310720u + 4194304u);
    char* p = ws + fixed;
    _Float16* gxf   = (_Float16*)p;   p += (size_t)Bc * 1048576u;
    _Float16* gxr   = (_Float16*)p;   p += (size_t)Bc * 1048576u;
    _Float16* hs    = (_Float16*)p;   p += (size_t)Bc * 524288u;
    _Float16* x0f16 = (_Float16*)p;   p += (size_t)Bc * 163840u;
    float* emis     = (float*)p;      p += (size_t)Bc * 11264u;
    unsigned char* bt = (unsigned char*)p;
    float* out = (float*)d_out;   // pred as floats [0,MM), loss at [MM]

    init_kernel<<<1, 256, 0, stream>>>(out, flags);
    conv_pad_kernel<<<(2048 * 80 + 255) / 256, 256, 0, stream>>>(w_ih_l0,  w0f, EE, 80, 2048 * 80);
    conv_pad_kernel<<<(2048 * 80 + 255) / 256, 256, 0, stream>>>(w_ih_l0r, w0r, EE, 80, 2048 * 80);
    conv_pad_kernel<<<(2048 * 256 + 255) / 256, 256, 0, stream>>>(w_ih_l1,  w1f, 1024, 256, 2048 * 256);
    conv_pad_kernel<<<(2048 * 256 + 255) / 256, 256, 0, stream>>>(w_ih_l1r, w1r, 1024, 256, 2048 * 256);

    const int nbg = Bc / 32;
    const int nchunk = BB / Bc;
    for (int cidx = 0; cidx < nchunk; ++cidx) {
        const int c0 = cidx * Bc;
        const int Mc = Bc * TT;
        dim3 gdim(GG / 128, Mc / 128);
        int* fl_l0 = flags + (cidx * 2 + 0) * 128;
        int* fl_l1 = flags + (cidx * 2 + 1) * 128;

        embed16_kernel<<<(Mc * 80 + 255) / 256, 256, 0, stream>>>(tokens + c0 * TT, emb, x0f16, Mc * 80);
        gemm_bt_kernel<<<gdim, 256, 0, stream>>>(x0f16, w0f, b_ih_l0,  b_hh_l0,  gxf, KP0);
        gemm_bt_kernel<<<gdim, 256, 0, stream>>>(x0f16, w0r, b_ih_l0r, b_hh_l0r, gxr, KP0);
        lstm_rec3_kernel<<<2 * nbg * 16, 256, 66560, stream>>>(
            gxf, gxr, w_hh_l0, w_hh_l0r, seqlen, c0, nbg, hs, hbuf, fl_l0);
        gemm_bt_kernel<<<gdim, 256, 0, stream>>>(hs, w1f, b_ih_l1,  b_hh_l1,  gxf, 1024);
        gemm_bt_kernel<<<gdim, 256, 0, stream>>>(hs, w1r, b_ih_l1r, b_hh_l1r, gxr, 1024);
        lstm_rec3_kernel<<<2 * nbg * 16, 256, 66560, stream>>>(
            gxf, gxr, w_hh_l1, w_hh_l1r, seqlen, c0, nbg, hs, hbuf, fl_l1);
        emis_kernel<<<(Mc * NC + 255) / 256, 256, 0, stream>>>(hs, fc_w, fc_b, emis, Mc * NC);
        crf_kernel<<<Bc, 64, 0, stream>>>(emis, seqlen, tags, trans, bt, out, c0);
    }
}